// Round 2
// 239.723 us; speedup vs baseline: 1.0168x; 1.0168x over previous
//
#include <hip/hip_runtime.h>
#include <math.h>

#define EPS 1e-6f

#define B_   16
#define T_   2048
#define LD   256
#define NB   32
#define BT   (B_ * T_)          // 32768
#define NCH  64
#define CHUNK (T_ / NCH)        // 32

typedef short bf16x8 __attribute__((ext_vector_type(8)));
typedef float f32x4  __attribute__((ext_vector_type(4)));

__device__ __forceinline__ unsigned short f2b(float f) {
    unsigned int u = __float_as_uint(f);
    unsigned int r = (u + 0x7fffu + ((u >> 16) & 1u)) >> 16;
    return (unsigned short)r;
}

__device__ __forceinline__ float b2f(unsigned short h) {
    return __uint_as_float(((unsigned int)h) << 16);
}

__device__ __forceinline__ void gl_lds16(const void* g, void* l) {
    __builtin_amdgcn_global_load_lds(
        (const __attribute__((address_space(1))) unsigned int*)g,
        (__attribute__((address_space(3))) unsigned int*)l, 16, 0, 0);
}

// Stage a 128-row x 32-col bf16 tile into LDS [128][32] with quad swizzle:
// physical quad p at row r holds logical quad qd = p ^ ((r>>1)&3).
__device__ __forceinline__ void stage_tile(const unsigned short* __restrict__ src,
                                           int row0, int stride, int kb,
                                           unsigned short* lds, int wv, int lane) {
#pragma unroll
    for (int cc = 0; cc < 2; ++cc) {
        int c = wv * 2 + cc;                 // chunk 0..7, 16 rows each
        int r = c * 16 + (lane >> 2);
        int qd = (lane & 3) ^ ((r >> 1) & 3);
        const unsigned short* g = src + (size_t)(row0 + r) * stride + kb + qd * 8;
        gl_lds16(g, lds + c * 512);          // wave-uniform LDS base; HW adds lane*16B
    }
}

__device__ __forceinline__ bf16x8 frag_ld(const unsigned short* lds, int row, int qd) {
    int pq = qd ^ ((row >> 1) & 3);
    return *(const bf16x8*)(lds + row * 32 + pq * 8);
}

// U buffer: [8 dc][32 i][32 dj] uint32, quad-swizzled within each 128B row:
// physical 8-uint quad p = (dj>>3) ^ (i&3).
__device__ __forceinline__ int u_idx(int i, int d) {
    return ((d >> 5) << 10) + (i << 5) + (((((d >> 3) & 3)) ^ (i & 3)) << 3) + (d & 7);
}

// ---------------------------------------------------------------------------
// Shared prolog for scan kernels: softmax P (bf16 hi/lo, swizzled) from logits,
// obs_s, then Am[i][d] = P @ AbT^T via MFMA (3-term hi/lo split) into U (fp32).
// Two barriers inside; on return U + obs_s are valid for all threads.
// ---------------------------------------------------------------------------
__device__ __forceinline__ void compute_Am(const float* __restrict__ logits,
                                           const float* __restrict__ obs,
                                           const unsigned short* __restrict__ AbTh,
                                           const unsigned short* __restrict__ AbTl,
                                           int bt0,
                                           unsigned int* U,
                                           unsigned short* Ph, unsigned short* Pl,
                                           float* obs_s) {
    int tid = threadIdx.x;
    int l = tid & 31, rg = tid >> 5;
    if (tid < CHUNK) obs_s[tid] = obs[bt0 + tid];
#pragma unroll
    for (int jj = 0; jj < 4; ++jj) {
        int row = rg * 4 + jj;
        float v = logits[(size_t)(bt0 + row) * NB + l];
        float mx = v;
#pragma unroll
        for (int off = 16; off >= 1; off >>= 1) mx = fmaxf(mx, __shfl_xor(mx, off, 32));
        float e = expf(v - mx);
        float s = e;
#pragma unroll
        for (int off = 16; off >= 1; off >>= 1) s += __shfl_xor(s, off, 32);
        float p = e / s;
        unsigned short h = f2b(p);
        int sa = row * 32 + ((((l >> 3) ^ ((row >> 1) & 3))) << 3) + (l & 7);
        Ph[sa] = h;
        Pl[sa] = f2b(p - b2f(h));
    }
    __syncthreads();

    int lane = tid & 63, wv = tid >> 6;
    int qd = lane >> 4, mr = lane & 15;
    bf16x8 ph[2], pl[2];
#pragma unroll
    for (int iT = 0; iT < 2; ++iT) {
        ph[iT] = frag_ld(Ph, iT * 16 + mr, qd);
        pl[iT] = frag_ld(Pl, iT * 16 + mr, qd);
    }
#pragma unroll
    for (int j = 0; j < 4; ++j) {
        int dcol = wv * 64 + j * 16 + mr;
        bf16x8 ah = *(const bf16x8*)(AbTh + dcol * NB + qd * 8);
        bf16x8 al = *(const bf16x8*)(AbTl + dcol * NB + qd * 8);
#pragma unroll
        for (int iT = 0; iT < 2; ++iT) {
            f32x4 acc = (f32x4){0.f, 0.f, 0.f, 0.f};
            acc = __builtin_amdgcn_mfma_f32_16x16x32_bf16(ph[iT], ah, acc, 0, 0, 0);
            acc = __builtin_amdgcn_mfma_f32_16x16x32_bf16(pl[iT], ah, acc, 0, 0, 0);
            acc = __builtin_amdgcn_mfma_f32_16x16x32_bf16(ph[iT], al, acc, 0, 0, 0);
#pragma unroll
            for (int r = 0; r < 4; ++r) {
                int i = iT * 16 + qd * 4 + r;
                U[u_idx(i, dcol)] = __float_as_uint(acc[r]);
            }
        }
    }
    __syncthreads();
}

// ---------------------------------------------------------------------------
// k_pre: ALL precompute in one launch, decoded by blockIdx.x (256 thr/block).
// ---------------------------------------------------------------------------
__global__ __launch_bounds__(256) void k_pre(const float* __restrict__ Z,
                                             const float* __restrict__ Dm,
                                             const float* __restrict__ cw,
                                             const float* __restrict__ Ew,
                                             const float* __restrict__ Bw,
                                             const float* __restrict__ Cw,
                                             const float* __restrict__ Mw,
                                             const float* __restrict__ imp,
                                             const float* __restrict__ ilv,
                                             const float* __restrict__ ylv,
                                             unsigned short* __restrict__ GMh,
                                             unsigned short* __restrict__ GCh,
                                             unsigned short* __restrict__ cwbh,
                                             float* __restrict__ im0,
                                             float* __restrict__ iv0,
                                             float* __restrict__ yv,
                                             unsigned short* __restrict__ AbTh,
                                             unsigned short* __restrict__ AbTl,
                                             unsigned short* __restrict__ Bwh,
                                             unsigned short* __restrict__ Zh) {
    int bid = blockIdx.x;
    int tid = threadIdx.x;
    if (bid < 544) {
        // small GEMM: out[f][d] = sum_e W[f][e] * E[e][d]
        const float* W; const float* E; unsigned short* out; int d0, f0;
        if (bid < 256)      { W = Mw; E = Ew; out = GMh;  d0 = (bid & 15) * 16; f0 = (bid >> 4) * 16; }
        else if (bid < 512) { W = Cw; E = Ew; out = GCh;  d0 = (bid & 15) * 16; f0 = ((bid - 256) >> 4) * 16; }
        else                { W = cw; E = Bw; out = cwbh; d0 = (bid & 15) * 16; f0 = ((bid - 512) >> 4) * 16; }
        __shared__ float Ws[16][17];
        __shared__ float Es[16][17];
        int tx = tid & 15, ty = tid >> 4;
        float acc = 0.f;
        for (int eb = 0; eb < LD; eb += 16) {
            Ws[ty][tx] = W[(f0 + ty) * LD + eb + tx];
            Es[ty][tx] = E[(eb + ty) * LD + d0 + tx];
            __syncthreads();
#pragma unroll
            for (int k = 0; k < 16; ++k) acc = fmaf(Ws[ty][k], Es[k][tx], acc);
            __syncthreads();
        }
        out[(f0 + ty) * LD + d0 + tx] = f2b(acc);
    } else if (bid < 577) {
        int sub = bid - 544;
        int t = tid;
        if (sub == 0) {
            float sm = 0.f, sv = 0.f;
            for (int k = 0; k < LD; ++k) {
                float e = Ew[k * LD + t];
                sm = fmaf(e, imp[k], sm);
                sv = fmaf(e * e, expf(ilv[k]) + EPS, sv);
            }
            im0[t] = sm;
            iv0[t] = sv;
            yv[t]  = expf(ylv[t]) + EPS;
        } else {
            int n = sub - 1;
            float a = -(expf(Dm[n * LD + t]) + EPS);
            unsigned short h = f2b(a);
            AbTh[t * NB + n] = h;
            AbTl[t * NB + n] = f2b(a - b2f(h));
        }
    } else if (bid < 641) {
        int i = (bid - 577) * 256 + tid;      // float4 index over 256*256/4
        float4 v = ((const float4*)Bw)[i];
        ((ushort4*)Bwh)[i] = make_ushort4(f2b(v.x), f2b(v.y), f2b(v.z), f2b(v.w));
    } else {
        int i = (bid - 641) * 256 + tid;      // float4 index over BT*LD/4
        float4 v = ((const float4*)Z)[i];
        ((ushort4*)Zh)[i] = make_ushort4(f2b(v.x), f2b(v.y), f2b(v.z), f2b(v.w));
    }
}

// ---------------------------------------------------------------------------
// k_zb: grid (BT/128, 3).
//  y<2 : alphas[:,y*128:(y+1)*128] = Zh @ Bwh^T   (fp32 out)
//  y==2: logits = Zh @ cwbh^T + cb                (fp32 out, N=32)
// ---------------------------------------------------------------------------
__global__ __launch_bounds__(256) void k_zb(const unsigned short* __restrict__ Zh,
                                            const unsigned short* __restrict__ Bwh,
                                            const unsigned short* __restrict__ cwbh,
                                            const float* __restrict__ cb,
                                            float* __restrict__ alphas,
                                            float* __restrict__ logits) {
    __shared__ unsigned short As[128 * 32];
    __shared__ unsigned short Bs[128 * 32];
    int tid = threadIdx.x, lane = tid & 63, wv = tid >> 6;
    int m0 = blockIdx.x * 128;
    int y  = blockIdx.y;
    if (y < 2) {
        int n0 = y * 128;
        int wm = (wv & 1) * 64, wn = (wv >> 1) * 64;
        f32x4 acc[4][4];
#pragma unroll
        for (int i = 0; i < 4; ++i)
#pragma unroll
            for (int j = 0; j < 4; ++j) acc[i][j] = (f32x4){0.f, 0.f, 0.f, 0.f};
        for (int kb = 0; kb < LD; kb += 32) {
            stage_tile(Zh, m0, LD, kb, As, wv, lane);
            stage_tile(Bwh, n0, LD, kb, Bs, wv, lane);
            __syncthreads();
            int qd = lane >> 4;
            bf16x8 af[4], bf[4];
#pragma unroll
            for (int i = 0; i < 4; ++i) af[i] = frag_ld(As, wm + i * 16 + (lane & 15), qd);
#pragma unroll
            for (int j = 0; j < 4; ++j) bf[j] = frag_ld(Bs, wn + j * 16 + (lane & 15), qd);
#pragma unroll
            for (int i = 0; i < 4; ++i)
#pragma unroll
                for (int j = 0; j < 4; ++j)
                    acc[i][j] = __builtin_amdgcn_mfma_f32_16x16x32_bf16(af[i], bf[j], acc[i][j], 0, 0, 0);
            __syncthreads();
        }
        int col = wn + (lane & 15);
        int rb  = wm + ((lane >> 4) << 2);
#pragma unroll
        for (int i = 0; i < 4; ++i)
#pragma unroll
            for (int j = 0; j < 4; ++j)
#pragma unroll
                for (int r = 0; r < 4; ++r)
                    alphas[(size_t)(m0 + rb + i * 16 + r) * LD + n0 + col + j * 16] = acc[i][j][r];
    } else {
        f32x4 acc[2][2];
#pragma unroll
        for (int i = 0; i < 2; ++i)
#pragma unroll
            for (int j = 0; j < 2; ++j) acc[i][j] = (f32x4){0.f, 0.f, 0.f, 0.f};
        for (int kb = 0; kb < LD; kb += 32) {
            stage_tile(Zh, m0, LD, kb, As, wv, lane);
            if (wv < 2) {
                int r = wv * 16 + (lane >> 2);
                int qd = (lane & 3) ^ ((r >> 1) & 3);
                gl_lds16(cwbh + (size_t)r * LD + kb + qd * 8, Bs + wv * 512);
            }
            __syncthreads();
            int qd = lane >> 4;
            bf16x8 af[2], bff[2];
#pragma unroll
            for (int i = 0; i < 2; ++i) af[i] = frag_ld(As, wv * 32 + i * 16 + (lane & 15), qd);
#pragma unroll
            for (int j = 0; j < 2; ++j) bff[j] = frag_ld(Bs, j * 16 + (lane & 15), qd);
#pragma unroll
            for (int i = 0; i < 2; ++i)
#pragma unroll
                for (int j = 0; j < 2; ++j)
                    acc[i][j] = __builtin_amdgcn_mfma_f32_16x16x32_bf16(af[i], bff[j], acc[i][j], 0, 0, 0);
            __syncthreads();
        }
        int col = lane & 15;
        int rb  = (lane >> 4) << 2;
#pragma unroll
        for (int i = 0; i < 2; ++i)
#pragma unroll
            for (int j = 0; j < 2; ++j)
#pragma unroll
                for (int r = 0; r < 4; ++r) {
                    int row = m0 + wv * 32 + i * 16 + rb + r;
                    int cc  = j * 16 + col;
                    logits[(size_t)row * NB + cc] = acc[i][j][r] + cb[cc];
                }
    }
}

// ---------------------------------------------------------------------------
// Pass 1: chunk totals.  Am via MFMA (compute_Am), then a cheap 32-step
// per-(d) recurrence reading one b32 per step.
// ---------------------------------------------------------------------------
__global__ __launch_bounds__(256) void k_tot(const float* __restrict__ logits,
                                             const float* __restrict__ alphas,
                                             const float* __restrict__ obs,
                                             const unsigned short* __restrict__ AbTh,
                                             const unsigned short* __restrict__ AbTl,
                                             float* __restrict__ totA,
                                             float* __restrict__ totBm,
                                             float* __restrict__ totBv) {
    __shared__ unsigned int U[8192];
    __shared__ unsigned short Ph[1024];
    __shared__ unsigned short Pl[1024];
    __shared__ float obs_s[CHUNK];
    int d = threadIdx.x;
    int bt0 = blockIdx.x * CHUNK;
    compute_Am(logits, obs, AbTh, AbTl, bt0, U, Ph, Pl, obs_s);

    float ra = 1.f, rm = 0.f, rv = 0.f;
    int ubase = ((d >> 5) << 10) + (d & 7);
    int qb = (d >> 3) & 3;
    for (int g = 0; g < 4; ++g) {
        float av[8];
#pragma unroll
        for (int k = 0; k < 8; ++k)
            av[k] = alphas[(size_t)(bt0 + g * 8 + k) * LD + d];
#pragma unroll
        for (int k = 0; k < 8; ++k) {
            int i = g * 8 + k;
            int ui = ubase + (i << 5) + ((qb ^ (i & 3)) << 3);
            float Am = __uint_as_float(U[ui]);
            float eAm = expf(Am * obs_s[i]);
            float ieA = 1.f / Am;
            float eBm = (eAm - 1.f) * ieA * av[k];
            float eBv = 0.5f * (eAm * eAm - 1.f) * ieA + EPS;
            rm = fmaf(eAm, rm, eBm);
            rv = fmaf(eAm * eAm, rv, eBv);
            ra *= eAm;
        }
    }
    int pidx = blockIdx.x * LD + d;
    totA[pidx] = ra; totBm[pidx] = rm; totBv[pidx] = rv;
}

// exclusive prefix over chunks per (b,d)
__global__ void k_chunkpfx(const float* __restrict__ totA, const float* __restrict__ totBm,
                           const float* __restrict__ totBv,
                           float* __restrict__ preA, float* __restrict__ preBm,
                           float* __restrict__ preBv) {
    int d = threadIdx.x;
    int b = blockIdx.x;
    float Pa = 1.f, Pm = 0.f, Pv = 0.f;
    for (int ch = 0; ch < NCH; ++ch) {
        int pidx = (b * NCH + ch) * LD + d;
        preA[pidx] = Pa; preBm[pidx] = Pm; preBv[pidx] = Pv;
        float a = totA[pidx], tm_ = totBm[pidx], tv = totBv[pidx];
        Pm = fmaf(a, Pm, tm_);
        Pv = fmaf(a * a, Pv, tv);
        Pa = a * Pa;
    }
}

// ---------------------------------------------------------------------------
// k_sms: fused pass 2 + output GEMMs.  One block per (b,chunk):
//   compute_Am (MFMA) -> scan overwrites U with packed (bf16 mm | bf16 ss)
//   -> barrier-free MFMA loop with A-frags unpacked from U / Zh and B-frags
//   (GMh/GCh, L2-resident) loaded straight from global.
// LDS: U 32KB | Ph/Pl 4KB | obs 128B  (~37KB; no Bs/Ms/Ss)
// ---------------------------------------------------------------------------
__global__ __launch_bounds__(256) void k_sms(const float* __restrict__ logits,
                                             const float* __restrict__ alphas,
                                             const float* __restrict__ obs,
                                             const unsigned short* __restrict__ AbTh,
                                             const unsigned short* __restrict__ AbTl,
                                             const float* __restrict__ preA,
                                             const float* __restrict__ preBm,
                                             const float* __restrict__ preBv,
                                             const float* __restrict__ im0,
                                             const float* __restrict__ iv0,
                                             const float* __restrict__ yv,
                                             const unsigned short* __restrict__ Zh,
                                             const unsigned short* __restrict__ GMh,
                                             const unsigned short* __restrict__ GCh,
                                             float* __restrict__ means,
                                             float* __restrict__ stds) {
    __shared__ unsigned int U[8192];
    __shared__ unsigned short Ph[1024];
    __shared__ unsigned short Pl[1024];
    __shared__ float obs_s[CHUNK];
    int tid = threadIdx.x;
    int d = tid;
    int bt0 = blockIdx.x * CHUNK;
    compute_Am(logits, obs, AbTh, AbTl, bt0, U, Ph, Pl, obs_s);

    int pidx = blockIdx.x * LD + d;
    float ga = preA[pidx], gm = preBm[pidx], gv = preBv[pidx];
    float i0 = im0[d], v0 = iv0[d], yvd = yv[d];
    int ubase = ((d >> 5) << 10) + (d & 7);
    int qb = (d >> 3) & 3;
    for (int g = 0; g < 4; ++g) {
        float av[8];
#pragma unroll
        for (int k = 0; k < 8; ++k)
            av[k] = alphas[(size_t)(bt0 + g * 8 + k) * LD + d];
#pragma unroll
        for (int k = 0; k < 8; ++k) {
            int i = g * 8 + k;
            int ui = ubase + (i << 5) + ((qb ^ (i & 3)) << 3);
            float Am = __uint_as_float(U[ui]);
            float eAm = expf(Am * obs_s[i]);
            float ieA = 1.f / Am;
            float eBm = (eAm - 1.f) * ieA * av[k];
            float eBv = 0.5f * (eAm * eAm - 1.f) * ieA + EPS;
            gm = fmaf(eAm, gm, eBm);
            gv = fmaf(eAm * eAm, gv, eBv);
            ga *= eAm;
            float mm = fmaf(ga, i0, gm);
            float vv = fmaf(ga * ga, v0, gv) + yvd;
            U[ui] = ((unsigned int)f2b(mm) << 16) | (unsigned int)f2b(sqrtf(vv));
        }
    }
    __syncthreads();

    // ---- barrier-free MFMA loop ----
    int lane = tid & 63, wv = tid >> 6;
    int qd = lane >> 4, mr = lane & 15;
    f32x4 accm[2][4], accs[2][4];
#pragma unroll
    for (int iT = 0; iT < 2; ++iT)
#pragma unroll
        for (int j = 0; j < 4; ++j) {
            accm[iT][j] = (f32x4){0.f, 0.f, 0.f, 0.f};
            accs[iT][j] = (f32x4){0.f, 0.f, 0.f, 0.f};
        }
    for (int kc = 0; kc < 8; ++kc) {
        bf16x8 am[2], asv[2], az[2];
#pragma unroll
        for (int iT = 0; iT < 2; ++iT) {
            int row = iT * 16 + mr;
            int off = (kc << 10) + (row << 5) + ((qd ^ (row & 3)) << 3);
            uint4 ua = *(const uint4*)(U + off);
            uint4 ub = *(const uint4*)(U + off + 4);
            unsigned int uu[8] = {ua.x, ua.y, ua.z, ua.w, ub.x, ub.y, ub.z, ub.w};
            bf16x8 m_, s_;
#pragma unroll
            for (int k = 0; k < 8; ++k) {
                m_[k] = (short)(uu[k] >> 16);
                s_[k] = (short)(uu[k] & 0xffffu);
            }
            am[iT] = m_; asv[iT] = s_;
            az[iT] = *(const bf16x8*)(Zh + (size_t)(bt0 + row) * LD + kc * 32 + qd * 8);
        }
#pragma unroll
        for (int j = 0; j < 4; ++j) {
            int brow = wv * 64 + j * 16 + mr;
            bf16x8 bm = *(const bf16x8*)(GMh + (size_t)brow * LD + kc * 32 + qd * 8);
            bf16x8 bc = *(const bf16x8*)(GCh + (size_t)brow * LD + kc * 32 + qd * 8);
#pragma unroll
            for (int iT = 0; iT < 2; ++iT) {
                accm[iT][j] = __builtin_amdgcn_mfma_f32_16x16x32_bf16(am[iT],  bm, accm[iT][j], 0, 0, 0);
                accs[iT][j] = __builtin_amdgcn_mfma_f32_16x16x32_bf16(asv[iT], bm, accs[iT][j], 0, 0, 0);
                accm[iT][j] = __builtin_amdgcn_mfma_f32_16x16x32_bf16(az[iT],  bc, accm[iT][j], 0, 0, 0);
            }
        }
    }

    // ---- epilogue ----
    int col0 = wv * 64 + mr;
    int rb   = (lane >> 4) << 2;
#pragma unroll
    for (int i = 0; i < 2; ++i)
#pragma unroll
        for (int j = 0; j < 4; ++j)
#pragma unroll
            for (int r = 0; r < 4; ++r) {
                size_t off = (size_t)(bt0 + i * 16 + rb + r) * LD + col0 + j * 16;
                means[off] = accm[i][j][r];
                stds[off]  = accs[i][j][r];
            }
}

// ---------------------------------------------------------------------------
extern "C" void kernel_launch(void* const* d_in, const int* in_sizes, int n_in,
                              void* d_out, int out_size, void* d_ws, size_t ws_size,
                              hipStream_t stream) {
    const float* Z   = (const float*)d_in[0];
    const float* obs = (const float*)d_in[1];
    const float* Dm  = (const float*)d_in[2];
    const float* cw  = (const float*)d_in[3];
    const float* cb  = (const float*)d_in[4];
    const float* Ew  = (const float*)d_in[5];
    const float* Bw  = (const float*)d_in[6];
    const float* Cw  = (const float*)d_in[7];
    const float* Mw  = (const float*)d_in[8];
    const float* imp = (const float*)d_in[9];
    const float* ilv = (const float*)d_in[10];
    const float* ylv = (const float*)d_in[11];

    float* out    = (float*)d_out;
    float* means  = out;
    float* stds   = out + (size_t)BT * LD;
    float* alphas = out + (size_t)2 * BT * LD;

    char* ws = (char*)d_ws;
    size_t o = 0;
    unsigned short* Zh   = (unsigned short*)(ws + o); o += (size_t)BT * LD * 2;   // 16MB
    float*          logits=(float*)(ws + o);          o += (size_t)BT * NB * 4;   // 4MB
    unsigned short* GMh  = (unsigned short*)(ws + o); o += (size_t)LD * LD * 2;
    unsigned short* GCh  = (unsigned short*)(ws + o); o += (size_t)LD * LD * 2;
    unsigned short* Bwh  = (unsigned short*)(ws + o); o += (size_t)LD * LD * 2;
    unsigned short* cwbh = (unsigned short*)(ws + o); o += (size_t)NB * LD * 2;
    unsigned short* AbTh = (unsigned short*)(ws + o); o += (size_t)LD * NB * 2;
    unsigned short* AbTl = (unsigned short*)(ws + o); o += (size_t)LD * NB * 2;
    float* totA  = (float*)(ws + o); o += (size_t)B_ * NCH * LD * 4;
    float* totBm = (float*)(ws + o); o += (size_t)B_ * NCH * LD * 4;
    float* totBv = (float*)(ws + o); o += (size_t)B_ * NCH * LD * 4;
    float* preA  = (float*)(ws + o); o += (size_t)B_ * NCH * LD * 4;
    float* preBm = (float*)(ws + o); o += (size_t)B_ * NCH * LD * 4;
    float* preBv = (float*)(ws + o); o += (size_t)B_ * NCH * LD * 4;
    float* im0   = (float*)(ws + o); o += LD * 4;
    float* iv0   = (float*)(ws + o); o += LD * 4;
    float* yv    = (float*)(ws + o); o += LD * 4;

    // 1. all precompute
    k_pre<<<dim3(641 + BT * LD / 1024), dim3(256), 0, stream>>>(
        Z, Dm, cw, Ew, Bw, Cw, Mw, imp, ilv, ylv,
        GMh, GCh, cwbh, im0, iv0, yv, AbTh, AbTl, Bwh, Zh);

    // 2. alphas + logits (both straight from Zh)
    k_zb<<<dim3(BT / 128, 3), dim3(256), 0, stream>>>(Zh, Bwh, cwbh, cb, alphas, logits);

    // 3-4. chunk totals + prefix
    k_tot<<<dim3(B_ * NCH), dim3(256), 0, stream>>>(logits, alphas, obs, AbTh, AbTl,
                                                    totA, totBm, totBv);
    k_chunkpfx<<<dim3(B_), dim3(LD), 0, stream>>>(totA, totBm, totBv, preA, preBm, preBv);

    // 5. fused scan + means/stds GEMMs
    k_sms<<<dim3(B_ * NCH), dim3(256), 0, stream>>>(logits, alphas, obs, AbTh, AbTl,
                                                    preA, preBm, preBv,
                                                    im0, iv0, yv,
                                                    Zh, GMh, GCh, means, stds);
}

// Round 4
// 237.045 us; speedup vs baseline: 1.0283x; 1.0113x over previous
//
#include <hip/hip_runtime.h>
#include <math.h>

#define EPS 1e-6f

#define B_   16
#define T_   2048
#define LD   256
#define NB   32
#define BT   (B_ * T_)          // 32768
#define NCH  64
#define CHUNK (T_ / NCH)        // 32

typedef short bf16x8 __attribute__((ext_vector_type(8)));
typedef float f32x4  __attribute__((ext_vector_type(4)));

__device__ __forceinline__ unsigned short f2b(float f) {
    unsigned int u = __float_as_uint(f);
    unsigned int r = (u + 0x7fffu + ((u >> 16) & 1u)) >> 16;
    return (unsigned short)r;
}

__device__ __forceinline__ float b2f(unsigned short h) {
    return __uint_as_float(((unsigned int)h) << 16);
}

__device__ __forceinline__ void gl_lds16(const void* g, void* l) {
    __builtin_amdgcn_global_load_lds(
        (const __attribute__((address_space(1))) unsigned int*)g,
        (__attribute__((address_space(3))) unsigned int*)l, 16, 0, 0);
}

// XCD-align map: hardware block wg (XCD = wg&7) -> work j with (j>>2)&7 == wg&7,
// so the consumer of 32-row slice j runs on the XCD where k_zb block j>>2 produced it.
// Bijective on [0,1024).
__device__ __forceinline__ int xcd_map(int wg) {
    int x = wg & 7, s = wg >> 3;
    return (s & 3) | (x << 2) | ((s >> 2) << 5);
}

// Stage a 128-row x 32-col bf16 tile into LDS [128][32] with quad swizzle:
// physical quad p at row r holds logical quad qd = p ^ ((r>>1)&3).
__device__ __forceinline__ void stage_tile(const unsigned short* __restrict__ src,
                                           int row0, int stride, int kb,
                                           unsigned short* lds, int wv, int lane) {
#pragma unroll
    for (int cc = 0; cc < 2; ++cc) {
        int c = wv * 2 + cc;                 // chunk 0..7, 16 rows each
        int r = c * 16 + (lane >> 2);
        int qd = (lane & 3) ^ ((r >> 1) & 3);
        const unsigned short* g = src + (size_t)(row0 + r) * stride + kb + qd * 8;
        gl_lds16(g, lds + c * 512);          // wave-uniform LDS base; HW adds lane*16B
    }
}

__device__ __forceinline__ bf16x8 frag_ld(const unsigned short* lds, int row, int qd) {
    int pq = qd ^ ((row >> 1) & 3);
    return *(const bf16x8*)(lds + row * 32 + pq * 8);
}

// U buffer: [8 dc][32 i][32 dj] uint32, quad-swizzled within each 128B row:
// physical 8-uint quad p = (dj>>3) ^ (i&3).
__device__ __forceinline__ int u_idx(int i, int d) {
    return ((d >> 5) << 10) + (i << 5) + (((((d >> 3) & 3)) ^ (i & 3)) << 3) + (d & 7);
}

// ---------------------------------------------------------------------------
// k_pre: ALL precompute in one launch, decoded by blockIdx.x (256 thr/block).
// ---------------------------------------------------------------------------
__global__ __launch_bounds__(256) void k_pre(const float* __restrict__ Z,
                                             const float* __restrict__ Dm,
                                             const float* __restrict__ cw,
                                             const float* __restrict__ Ew,
                                             const float* __restrict__ Bw,
                                             const float* __restrict__ Cw,
                                             const float* __restrict__ Mw,
                                             const float* __restrict__ imp,
                                             const float* __restrict__ ilv,
                                             const float* __restrict__ ylv,
                                             unsigned short* __restrict__ GMh,
                                             unsigned short* __restrict__ GCh,
                                             unsigned short* __restrict__ cwbh,
                                             float* __restrict__ im0,
                                             float* __restrict__ iv0,
                                             float* __restrict__ yv,
                                             unsigned short* __restrict__ AbTh,
                                             unsigned short* __restrict__ AbTl,
                                             unsigned short* __restrict__ Bwh,
                                             unsigned short* __restrict__ Zh) {
    int bid = blockIdx.x;
    int tid = threadIdx.x;
    if (bid < 544) {
        // small GEMM: out[f][d] = sum_e W[f][e] * E[e][d]
        const float* W; const float* E; unsigned short* out; int d0, f0;
        if (bid < 256)      { W = Mw; E = Ew; out = GMh;  d0 = (bid & 15) * 16; f0 = (bid >> 4) * 16; }
        else if (bid < 512) { W = Cw; E = Ew; out = GCh;  d0 = (bid & 15) * 16; f0 = ((bid - 256) >> 4) * 16; }
        else                { W = cw; E = Bw; out = cwbh; d0 = (bid & 15) * 16; f0 = ((bid - 512) >> 4) * 16; }
        __shared__ float Ws[16][17];
        __shared__ float Es[16][17];
        int tx = tid & 15, ty = tid >> 4;
        float acc = 0.f;
        for (int eb = 0; eb < LD; eb += 16) {
            Ws[ty][tx] = W[(f0 + ty) * LD + eb + tx];
            Es[ty][tx] = E[(eb + ty) * LD + d0 + tx];
            __syncthreads();
#pragma unroll
            for (int k = 0; k < 16; ++k) acc = fmaf(Ws[ty][k], Es[k][tx], acc);
            __syncthreads();
        }
        out[(f0 + ty) * LD + d0 + tx] = f2b(acc);
    } else if (bid < 577) {
        int sub = bid - 544;
        int t = tid;
        if (sub == 0) {
            float sm = 0.f, sv = 0.f;
            for (int k = 0; k < LD; ++k) {
                float e = Ew[k * LD + t];
                sm = fmaf(e, imp[k], sm);
                sv = fmaf(e * e, expf(ilv[k]) + EPS, sv);
            }
            im0[t] = sm;
            iv0[t] = sv;
            yv[t]  = expf(ylv[t]) + EPS;
        } else {
            int n = sub - 1;
            float a = -(expf(Dm[n * LD + t]) + EPS);
            unsigned short h = f2b(a);
            AbTh[t * NB + n] = h;
            AbTl[t * NB + n] = f2b(a - b2f(h));
        }
    } else if (bid < 641) {
        int i = (bid - 577) * 256 + tid;      // float4 index over 256*256/4
        float4 v = ((const float4*)Bw)[i];
        ((ushort4*)Bwh)[i] = make_ushort4(f2b(v.x), f2b(v.y), f2b(v.z), f2b(v.w));
    } else {
        int i = (bid - 641) * 256 + tid;      // float4 index over BT*LD/4
        float4 v = ((const float4*)Z)[i];
        ((ushort4*)Zh)[i] = make_ushort4(f2b(v.x), f2b(v.y), f2b(v.z), f2b(v.w));
    }
}

// ---------------------------------------------------------------------------
// k_zb: grid (BT/128, 3).
//  y<2 : alphas[:,y*128:(y+1)*128] = Zh @ Bwh^T   (fp32 out)
//  y==2: logits = Zh @ cwbh^T + cb                (fp32 out, N=32)
// ---------------------------------------------------------------------------
__global__ __launch_bounds__(256) void k_zb(const unsigned short* __restrict__ Zh,
                                            const unsigned short* __restrict__ Bwh,
                                            const unsigned short* __restrict__ cwbh,
                                            const float* __restrict__ cb,
                                            float* __restrict__ alphas,
                                            float* __restrict__ logits) {
    __shared__ unsigned short As[128 * 32];
    __shared__ unsigned short Bs[128 * 32];
    int tid = threadIdx.x, lane = tid & 63, wv = tid >> 6;
    int m0 = blockIdx.x * 128;
    int y  = blockIdx.y;
    if (y < 2) {
        int n0 = y * 128;
        int wm = (wv & 1) * 64, wn = (wv >> 1) * 64;
        f32x4 acc[4][4];
#pragma unroll
        for (int i = 0; i < 4; ++i)
#pragma unroll
            for (int j = 0; j < 4; ++j) acc[i][j] = (f32x4){0.f, 0.f, 0.f, 0.f};
        for (int kb = 0; kb < LD; kb += 32) {
            stage_tile(Zh, m0, LD, kb, As, wv, lane);
            stage_tile(Bwh, n0, LD, kb, Bs, wv, lane);
            __syncthreads();
            int qd = lane >> 4;
            bf16x8 af[4], bf[4];
#pragma unroll
            for (int i = 0; i < 4; ++i) af[i] = frag_ld(As, wm + i * 16 + (lane & 15), qd);
#pragma unroll
            for (int j = 0; j < 4; ++j) bf[j] = frag_ld(Bs, wn + j * 16 + (lane & 15), qd);
#pragma unroll
            for (int i = 0; i < 4; ++i)
#pragma unroll
                for (int j = 0; j < 4; ++j)
                    acc[i][j] = __builtin_amdgcn_mfma_f32_16x16x32_bf16(af[i], bf[j], acc[i][j], 0, 0, 0);
            __syncthreads();
        }
        int col = wn + (lane & 15);
        int rb  = wm + ((lane >> 4) << 2);
#pragma unroll
        for (int i = 0; i < 4; ++i)
#pragma unroll
            for (int j = 0; j < 4; ++j)
#pragma unroll
                for (int r = 0; r < 4; ++r)
                    alphas[(size_t)(m0 + rb + i * 16 + r) * LD + n0 + col + j * 16] = acc[i][j][r];
    } else {
        f32x4 acc[2][2];
#pragma unroll
        for (int i = 0; i < 2; ++i)
#pragma unroll
            for (int j = 0; j < 2; ++j) acc[i][j] = (f32x4){0.f, 0.f, 0.f, 0.f};
        for (int kb = 0; kb < LD; kb += 32) {
            stage_tile(Zh, m0, LD, kb, As, wv, lane);
            if (wv < 2) {
                int r = wv * 16 + (lane >> 2);
                int qd = (lane & 3) ^ ((r >> 1) & 3);
                gl_lds16(cwbh + (size_t)r * LD + kb + qd * 8, Bs + wv * 512);
            }
            __syncthreads();
            int qd = lane >> 4;
            bf16x8 af[2], bff[2];
#pragma unroll
            for (int i = 0; i < 2; ++i) af[i] = frag_ld(As, wv * 32 + i * 16 + (lane & 15), qd);
#pragma unroll
            for (int j = 0; j < 2; ++j) bff[j] = frag_ld(Bs, j * 16 + (lane & 15), qd);
#pragma unroll
            for (int i = 0; i < 2; ++i)
#pragma unroll
                for (int j = 0; j < 2; ++j)
                    acc[i][j] = __builtin_amdgcn_mfma_f32_16x16x32_bf16(af[i], bff[j], acc[i][j], 0, 0, 0);
            __syncthreads();
        }
        int col = lane & 15;
        int rb  = (lane >> 4) << 2;
#pragma unroll
        for (int i = 0; i < 2; ++i)
#pragma unroll
            for (int j = 0; j < 2; ++j)
#pragma unroll
                for (int r = 0; r < 4; ++r) {
                    int row = m0 + wv * 32 + i * 16 + rb + r;
                    int cc  = j * 16 + col;
                    logits[(size_t)row * NB + cc] = acc[i][j][r] + cb[cc];
                }
    }
}

// ---------------------------------------------------------------------------
// k_tot: chunk totals.  Softmax from logits -> P (bf16 hi/lo) staged to LDS
// AND written back (packed hi|lo uint32, fragment-swizzled) over the logits
// buffer for k_sms.  Am via 3-term MFMA -> U.  Scan with prefetched alphas.
// ---------------------------------------------------------------------------
__global__ __launch_bounds__(256) void k_tot(float* __restrict__ logits,
                                             const float* __restrict__ alphas,
                                             const float* __restrict__ obs,
                                             const unsigned short* __restrict__ AbTh,
                                             const unsigned short* __restrict__ AbTl,
                                             float* __restrict__ totA,
                                             float* __restrict__ totBm,
                                             float* __restrict__ totBv) {
    __shared__ unsigned int U[8192];
    __shared__ unsigned short Ph[1024];
    __shared__ unsigned short Pl[1024];
    int tid = threadIdx.x;
    int d = tid;
    int bid = xcd_map(blockIdx.x);
    int bt0 = bid * CHUNK;

    // early prefetch: all 32 alphas for this column
    float av[32];
#pragma unroll
    for (int i = 0; i < 32; ++i) av[i] = alphas[(size_t)(bt0 + i) * LD + d];

    // softmax + P writeback (packed, swizzled)
    int l = tid & 31, rg = tid >> 5;
    unsigned int* Pg = (unsigned int*)logits + (size_t)bt0 * NB;
#pragma unroll
    for (int jj = 0; jj < 4; ++jj) {
        int row = rg * 4 + jj;
        float v = logits[(size_t)(bt0 + row) * NB + l];
        float mx = v;
#pragma unroll
        for (int off = 16; off >= 1; off >>= 1) mx = fmaxf(mx, __shfl_xor(mx, off, 32));
        float e = __expf(v - mx);
        float s = e;
#pragma unroll
        for (int off = 16; off >= 1; off >>= 1) s += __shfl_xor(s, off, 32);
        float p = e * __builtin_amdgcn_rcpf(s);
        unsigned short h = f2b(p);
        unsigned short lo = f2b(p - b2f(h));
        int sa = row * 32 + ((((l >> 3) ^ ((row >> 1) & 3))) << 3) + (l & 7);
        Ph[sa] = h;
        Pl[sa] = lo;
        Pg[sa] = ((unsigned int)h << 16) | (unsigned int)lo;   // same wave read row first
    }
    __syncthreads();

    // Am = P @ AbT^T (3-term hi/lo) -> U (fp32)
    int lane = tid & 63, wv = tid >> 6;
    int qd = lane >> 4, mr = lane & 15;
    bf16x8 ph[2], pl[2];
#pragma unroll
    for (int iT = 0; iT < 2; ++iT) {
        ph[iT] = frag_ld(Ph, iT * 16 + mr, qd);
        pl[iT] = frag_ld(Pl, iT * 16 + mr, qd);
    }
#pragma unroll
    for (int j = 0; j < 4; ++j) {
        int dcol = wv * 64 + j * 16 + mr;
        bf16x8 ah = *(const bf16x8*)(AbTh + dcol * NB + qd * 8);
        bf16x8 al = *(const bf16x8*)(AbTl + dcol * NB + qd * 8);
#pragma unroll
        for (int iT = 0; iT < 2; ++iT) {
            f32x4 acc = (f32x4){0.f, 0.f, 0.f, 0.f};
            acc = __builtin_amdgcn_mfma_f32_16x16x32_bf16(ph[iT], ah, acc, 0, 0, 0);
            acc = __builtin_amdgcn_mfma_f32_16x16x32_bf16(pl[iT], ah, acc, 0, 0, 0);
            acc = __builtin_amdgcn_mfma_f32_16x16x32_bf16(ph[iT], al, acc, 0, 0, 0);
#pragma unroll
            for (int r = 0; r < 4; ++r)
                U[u_idx(iT * 16 + qd * 4 + r, dcol)] = __float_as_uint(acc[r]);
        }
    }
    __syncthreads();

    // scan
    float ra = 1.f, rm = 0.f, rv = 0.f;
    int ubase = ((d >> 5) << 10) + (d & 7);
    int qb = (d >> 3) & 3;
#pragma unroll
    for (int i = 0; i < CHUNK; ++i) {
        int ui = ubase + (i << 5) + ((qb ^ (i & 3)) << 3);
        float Am = __uint_as_float(U[ui]);
        float tt = obs[bt0 + i];
        float eAm = __expf(Am * tt);
        float ieA = __builtin_amdgcn_rcpf(Am);
        float e2  = eAm * eAm;
        float eBm = (eAm - 1.f) * ieA * av[i];
        float eBv = fmaf(0.5f * (e2 - 1.f), ieA, EPS);
        rm = fmaf(eAm, rm, eBm);
        rv = fmaf(e2, rv, eBv);
        ra *= eAm;
    }
    int pidx = bid * LD + d;
    totA[pidx] = ra; totBm[pidx] = rm; totBv[pidx] = rv;
}

// exclusive prefix over chunks per (b,d), batched loads (8 ahead)
__global__ __launch_bounds__(256) void k_chunkpfx(const float* __restrict__ totA,
                                                  const float* __restrict__ totBm,
                                                  const float* __restrict__ totBv,
                                                  float* __restrict__ preA,
                                                  float* __restrict__ preBm,
                                                  float* __restrict__ preBv) {
    int d = threadIdx.x;
    int b = blockIdx.x;
    float Pa = 1.f, Pm = 0.f, Pv = 0.f;
    for (int g = 0; g < 8; ++g) {
        float a8[8], m8[8], v8[8];
#pragma unroll
        for (int k = 0; k < 8; ++k) {
            int pidx = (b * NCH + g * 8 + k) * LD + d;
            a8[k] = totA[pidx]; m8[k] = totBm[pidx]; v8[k] = totBv[pidx];
        }
#pragma unroll
        for (int k = 0; k < 8; ++k) {
            int pidx = (b * NCH + g * 8 + k) * LD + d;
            preA[pidx] = Pa; preBm[pidx] = Pm; preBv[pidx] = Pv;
            Pm = fmaf(a8[k], Pm, m8[k]);
            Pv = fmaf(a8[k] * a8[k], Pv, v8[k]);
            Pa *= a8[k];
        }
    }
}

// ---------------------------------------------------------------------------
// k_sms: fused pass 2 + output GEMMs.  One block per (b,chunk):
//   P frags straight from global (packed by k_tot) -> Am MFMA -> U ->
//   scan (register alphas) -> barrier-free MFMA GEMM phase.
// LDS: U 32KB only.
// ---------------------------------------------------------------------------
__global__ __launch_bounds__(256) void k_sms(const float* __restrict__ logits,
                                             const float* __restrict__ alphas,
                                             const float* __restrict__ obs,
                                             const unsigned short* __restrict__ AbTh,
                                             const unsigned short* __restrict__ AbTl,
                                             const float* __restrict__ preA,
                                             const float* __restrict__ preBm,
                                             const float* __restrict__ preBv,
                                             const float* __restrict__ im0,
                                             const float* __restrict__ iv0,
                                             const float* __restrict__ yv,
                                             const unsigned short* __restrict__ Zh,
                                             const unsigned short* __restrict__ GMh,
                                             const unsigned short* __restrict__ GCh,
                                             float* __restrict__ means,
                                             float* __restrict__ stds) {
    __shared__ unsigned int U[8192];
    int tid = threadIdx.x, lane = tid & 63, wv = tid >> 6;
    int d = tid;
    int bid = xcd_map(blockIdx.x);
    int bt0 = bid * CHUNK;

    // ---- early prefetch: alphas column + carry-ins (all in flight at once) ----
    float av[32];
#pragma unroll
    for (int i = 0; i < 32; ++i) av[i] = alphas[(size_t)(bt0 + i) * LD + d];
    int pidx = bid * LD + d;
    float ga = preA[pidx], gm = preBm[pidx], gv = preBv[pidx];
    float i0 = im0[d], v0 = iv0[d], yvd = yv[d];

    // ---- P fragments straight from global (packed hi|lo, pre-swizzled) ----
    int qd = lane >> 4, mr = lane & 15;
    const unsigned int* Pg = (const unsigned int*)logits + (size_t)bt0 * NB;
    bf16x8 ph[2], pl[2];
#pragma unroll
    for (int iT = 0; iT < 2; ++iT) {
        int row = iT * 16 + mr;
        int pq = qd ^ ((row >> 1) & 3);
        const uint4* q = (const uint4*)(Pg + row * 32 + pq * 8);
        uint4 wa = q[0], wb = q[1];
        unsigned int w[8] = {wa.x, wa.y, wa.z, wa.w, wb.x, wb.y, wb.z, wb.w};
        bf16x8 hh, ll;
#pragma unroll
        for (int k = 0; k < 8; ++k) {
            hh[k] = (short)(w[k] >> 16);
            ll[k] = (short)(w[k] & 0xffffu);
        }
        ph[iT] = hh; pl[iT] = ll;
    }

    // ---- Am = P @ AbT^T (3-term) -> U (fp32) ----
#pragma unroll
    for (int j = 0; j < 4; ++j) {
        int dcol = wv * 64 + j * 16 + mr;
        bf16x8 ah = *(const bf16x8*)(AbTh + dcol * NB + qd * 8);
        bf16x8 al = *(const bf16x8*)(AbTl + dcol * NB + qd * 8);
#pragma unroll
        for (int iT = 0; iT < 2; ++iT) {
            f32x4 acc = (f32x4){0.f, 0.f, 0.f, 0.f};
            acc = __builtin_amdgcn_mfma_f32_16x16x32_bf16(ph[iT], ah, acc, 0, 0, 0);
            acc = __builtin_amdgcn_mfma_f32_16x16x32_bf16(pl[iT], ah, acc, 0, 0, 0);
            acc = __builtin_amdgcn_mfma_f32_16x16x32_bf16(ph[iT], al, acc, 0, 0, 0);
#pragma unroll
            for (int r = 0; r < 4; ++r)
                U[u_idx(iT * 16 + qd * 4 + r, dcol)] = __float_as_uint(acc[r]);
        }
    }
    __syncthreads();

    // ---- scan: register alphas, manual bf16 pack (HW-verified path) ----
    int ubase = ((d >> 5) << 10) + (d & 7);
    int qb = (d >> 3) & 3;
#pragma unroll
    for (int i = 0; i < CHUNK; ++i) {
        int ui = ubase + (i << 5) + ((qb ^ (i & 3)) << 3);
        float Am = __uint_as_float(U[ui]);
        float tt = obs[bt0 + i];
        float eAm = __expf(Am * tt);
        float ieA = __builtin_amdgcn_rcpf(Am);
        float e2  = eAm * eAm;
        float eBm = (eAm - 1.f) * ieA * av[i];
        float eBv = fmaf(0.5f * (e2 - 1.f), ieA, EPS);
        gm = fmaf(eAm, gm, eBm);
        gv = fmaf(e2, gv, eBv);
        ga *= eAm;
        float mm = fmaf(ga, i0, gm);
        float vv = fmaf(ga * ga, v0, gv) + yvd;
        float ss = sqrtf(vv);
        U[ui] = ((unsigned int)f2b(mm) << 16) | (unsigned int)f2b(ss);
    }
    __syncthreads();

    // ---- barrier-free MFMA GEMM phase ----
    f32x4 accm[2][4], accs[2][4];
#pragma unroll
    for (int iT = 0; iT < 2; ++iT)
#pragma unroll
        for (int j = 0; j < 4; ++j) {
            accm[iT][j] = (f32x4){0.f, 0.f, 0.f, 0.f};
            accs[iT][j] = (f32x4){0.f, 0.f, 0.f, 0.f};
        }
    for (int kc = 0; kc < 8; ++kc) {
        bf16x8 am[2], asv[2], az[2];
#pragma unroll
        for (int iT = 0; iT < 2; ++iT) {
            int row = iT * 16 + mr;
            int off = (kc << 10) + (row << 5) + ((qd ^ (row & 3)) << 3);
            uint4 ua = *(const uint4*)(U + off);
            uint4 ub = *(const uint4*)(U + off + 4);
            unsigned int uu[8] = {ua.x, ua.y, ua.z, ua.w, ub.x, ub.y, ub.z, ub.w};
            bf16x8 m_, s_;
#pragma unroll
            for (int k = 0; k < 8; ++k) {
                m_[k] = (short)(uu[k] >> 16);
                s_[k] = (short)(uu[k] & 0xffffu);
            }
            am[iT] = m_; asv[iT] = s_;
            az[iT] = *(const bf16x8*)(Zh + (size_t)(bt0 + row) * LD + kc * 32 + qd * 8);
        }
#pragma unroll
        for (int j = 0; j < 4; ++j) {
            int brow = wv * 64 + j * 16 + mr;
            bf16x8 bm = *(const bf16x8*)(GMh + (size_t)brow * LD + kc * 32 + qd * 8);
            bf16x8 bc = *(const bf16x8*)(GCh + (size_t)brow * LD + kc * 32 + qd * 8);
#pragma unroll
            for (int iT = 0; iT < 2; ++iT) {
                accm[iT][j] = __builtin_amdgcn_mfma_f32_16x16x32_bf16(am[iT],  bm, accm[iT][j], 0, 0, 0);
                accs[iT][j] = __builtin_amdgcn_mfma_f32_16x16x32_bf16(asv[iT], bm, accs[iT][j], 0, 0, 0);
                accm[iT][j] = __builtin_amdgcn_mfma_f32_16x16x32_bf16(az[iT],  bc, accm[iT][j], 0, 0, 0);
            }
        }
    }

    // ---- epilogue ----
    int col0 = wv * 64 + mr;
    int rb   = (lane >> 4) << 2;
#pragma unroll
    for (int i = 0; i < 2; ++i)
#pragma unroll
        for (int j = 0; j < 4; ++j)
#pragma unroll
            for (int r = 0; r < 4; ++r) {
                size_t off = (size_t)(bt0 + i * 16 + rb + r) * LD + col0 + j * 16;
                means[off] = accm[i][j][r];
                stds[off]  = accs[i][j][r];
            }
}

// ---------------------------------------------------------------------------
extern "C" void kernel_launch(void* const* d_in, const int* in_sizes, int n_in,
                              void* d_out, int out_size, void* d_ws, size_t ws_size,
                              hipStream_t stream) {
    const float* Z   = (const float*)d_in[0];
    const float* obs = (const float*)d_in[1];
    const float* Dm  = (const float*)d_in[2];
    const float* cw  = (const float*)d_in[3];
    const float* cb  = (const float*)d_in[4];
    const float* Ew  = (const float*)d_in[5];
    const float* Bw  = (const float*)d_in[6];
    const float* Cw  = (const float*)d_in[7];
    const float* Mw  = (const float*)d_in[8];
    const float* imp = (const float*)d_in[9];
    const float* ilv = (const float*)d_in[10];
    const float* ylv = (const float*)d_in[11];

    float* out    = (float*)d_out;
    float* means  = out;
    float* stds   = out + (size_t)BT * LD;
    float* alphas = out + (size_t)2 * BT * LD;

    char* ws = (char*)d_ws;
    size_t o = 0;
    unsigned short* Zh   = (unsigned short*)(ws + o); o += (size_t)BT * LD * 2;   // 16MB
    float*          logits=(float*)(ws + o);          o += (size_t)BT * NB * 4;   // 4MB
    unsigned short* GMh  = (unsigned short*)(ws + o); o += (size_t)LD * LD * 2;
    unsigned short* GCh  = (unsigned short*)(ws + o); o += (size_t)LD * LD * 2;
    unsigned short* Bwh  = (unsigned short*)(ws + o); o += (size_t)LD * LD * 2;
    unsigned short* cwbh = (unsigned short*)(ws + o); o += (size_t)NB * LD * 2;
    unsigned short* AbTh = (unsigned short*)(ws + o); o += (size_t)LD * NB * 2;
    unsigned short* AbTl = (unsigned short*)(ws + o); o += (size_t)LD * NB * 2;
    float* totA  = (float*)(ws + o); o += (size_t)B_ * NCH * LD * 4;
    float* totBm = (float*)(ws + o); o += (size_t)B_ * NCH * LD * 4;
    float* totBv = (float*)(ws + o); o += (size_t)B_ * NCH * LD * 4;
    float* preA  = (float*)(ws + o); o += (size_t)B_ * NCH * LD * 4;
    float* preBm = (float*)(ws + o); o += (size_t)B_ * NCH * LD * 4;
    float* preBv = (float*)(ws + o); o += (size_t)B_ * NCH * LD * 4;
    float* im0   = (float*)(ws + o); o += LD * 4;
    float* iv0   = (float*)(ws + o); o += LD * 4;
    float* yv    = (float*)(ws + o); o += LD * 4;

    // 1. all precompute
    k_pre<<<dim3(641 + BT * LD / 1024), dim3(256), 0, stream>>>(
        Z, Dm, cw, Ew, Bw, Cw, Mw, imp, ilv, ylv,
        GMh, GCh, cwbh, im0, iv0, yv, AbTh, AbTl, Bwh, Zh);

    // 2. alphas + logits (both straight from Zh)
    k_zb<<<dim3(BT / 128, 3), dim3(256), 0, stream>>>(Zh, Bwh, cwbh, cb, alphas, logits);

    // 3-4. chunk totals (+ P packing into logits) + prefix
    k_tot<<<dim3(B_ * NCH), dim3(256), 0, stream>>>(logits, alphas, obs, AbTh, AbTl,
                                                    totA, totBm, totBv);
    k_chunkpfx<<<dim3(B_), dim3(LD), 0, stream>>>(totA, totBm, totBv, preA, preBm, preBv);

    // 5. fused scan + means/stds GEMMs
    k_sms<<<dim3(B_ * NCH), dim3(256), 0, stream>>>(logits, alphas, obs, AbTh, AbTl,
                                                    preA, preBm, preBv,
                                                    im0, iv0, yv,
                                                    Zh, GMh, GCh, means, stds);
}

// Round 6
// 235.636 us; speedup vs baseline: 1.0344x; 1.0060x over previous
//
#include <hip/hip_runtime.h>
#include <math.h>

#define EPS 1e-6f

#define B_   16
#define T_   2048
#define LD   256
#define NB   32
#define BT   (B_ * T_)          // 32768
#define NCH  64
#define CHUNK (T_ / NCH)        // 32

typedef short bf16x8 __attribute__((ext_vector_type(8)));
typedef float f32x4  __attribute__((ext_vector_type(4)));

__device__ __forceinline__ unsigned short f2b(float f) {
    unsigned int u = __float_as_uint(f);
    unsigned int r = (u + 0x7fffu + ((u >> 16) & 1u)) >> 16;
    return (unsigned short)r;
}

__device__ __forceinline__ float b2f(unsigned short h) {
    return __uint_as_float(((unsigned int)h) << 16);
}

__device__ __forceinline__ void gl_lds16(const void* g, void* l) {
    __builtin_amdgcn_global_load_lds(
        (const __attribute__((address_space(1))) unsigned int*)g,
        (__attribute__((address_space(3))) unsigned int*)l, 16, 0, 0);
}

// XCD-align map (k_tot only): hardware block wg (XCD = wg&7) -> work j with
// (j>>2)&7 == wg&7.  Bijective on [0,1024).
__device__ __forceinline__ int xcd_map(int wg) {
    int x = wg & 7, s = wg >> 3;
    return (s & 3) | (x << 2) | ((s >> 2) << 5);
}

// Stage a 128-row x 32-col bf16 tile into LDS [128][32] with quad swizzle:
// physical quad p at row r holds logical quad qd = p ^ ((r>>1)&3).
__device__ __forceinline__ void stage_tile(const unsigned short* __restrict__ src,
                                           int row0, int stride, int kb,
                                           unsigned short* lds, int wv, int lane) {
#pragma unroll
    for (int cc = 0; cc < 2; ++cc) {
        int c = wv * 2 + cc;                 // chunk 0..7, 16 rows each
        int r = c * 16 + (lane >> 2);
        int qd = (lane & 3) ^ ((r >> 1) & 3);
        const unsigned short* g = src + (size_t)(row0 + r) * stride + kb + qd * 8;
        gl_lds16(g, lds + c * 512);          // wave-uniform LDS base; HW adds lane*16B
    }
}

__device__ __forceinline__ bf16x8 frag_ld(const unsigned short* lds, int row, int qd) {
    int pq = qd ^ ((row >> 1) & 3);
    return *(const bf16x8*)(lds + row * 32 + pq * 8);
}

// U buffer: [8 dc][32 i][32 dj] uint32, quad-swizzled within each 128B row:
// physical 8-uint quad p = (dj>>3) ^ (i&3).
__device__ __forceinline__ int u_idx(int i, int d) {
    return ((d >> 5) << 10) + (i << 5) + (((((d >> 3) & 3)) ^ (i & 3)) << 3) + (d & 7);
}

// ---------------------------------------------------------------------------
// k_pre: ALL precompute in one launch, decoded by blockIdx.x (256 thr/block).
// ---------------------------------------------------------------------------
__global__ __launch_bounds__(256) void k_pre(const float* __restrict__ Z,
                                             const float* __restrict__ Dm,
                                             const float* __restrict__ cw,
                                             const float* __restrict__ Ew,
                                             const float* __restrict__ Bw,
                                             const float* __restrict__ Cw,
                                             const float* __restrict__ Mw,
                                             const float* __restrict__ imp,
                                             const float* __restrict__ ilv,
                                             const float* __restrict__ ylv,
                                             unsigned short* __restrict__ GMh,
                                             unsigned short* __restrict__ GCh,
                                             unsigned short* __restrict__ cwbh,
                                             float* __restrict__ im0,
                                             float* __restrict__ iv0,
                                             float* __restrict__ yv,
                                             unsigned short* __restrict__ AbTh,
                                             unsigned short* __restrict__ AbTl,
                                             unsigned short* __restrict__ Bwh,
                                             unsigned short* __restrict__ Zh) {
    int bid = blockIdx.x;
    int tid = threadIdx.x;
    if (bid < 544) {
        // small GEMM: out[f][d] = sum_e W[f][e] * E[e][d]
        const float* W; const float* E; unsigned short* out; int d0, f0;
        if (bid < 256)      { W = Mw; E = Ew; out = GMh;  d0 = (bid & 15) * 16; f0 = (bid >> 4) * 16; }
        else if (bid < 512) { W = Cw; E = Ew; out = GCh;  d0 = (bid & 15) * 16; f0 = ((bid - 256) >> 4) * 16; }
        else                { W = cw; E = Bw; out = cwbh; d0 = (bid & 15) * 16; f0 = ((bid - 512) >> 4) * 16; }
        __shared__ float Ws[16][17];
        __shared__ float Es[16][17];
        int tx = tid & 15, ty = tid >> 4;
        float acc = 0.f;
        for (int eb = 0; eb < LD; eb += 16) {
            Ws[ty][tx] = W[(f0 + ty) * LD + eb + tx];
            Es[ty][tx] = E[(eb + ty) * LD + d0 + tx];
            __syncthreads();
#pragma unroll
            for (int k = 0; k < 16; ++k) acc = fmaf(Ws[ty][k], Es[k][tx], acc);
            __syncthreads();
        }
        out[(f0 + ty) * LD + d0 + tx] = f2b(acc);
    } else if (bid < 577) {
        int sub = bid - 544;
        int t = tid;
        if (sub == 0) {
            float sm = 0.f, sv = 0.f;
            for (int k = 0; k < LD; ++k) {
                float e = Ew[k * LD + t];
                sm = fmaf(e, imp[k], sm);
                sv = fmaf(e * e, expf(ilv[k]) + EPS, sv);
            }
            im0[t] = sm;
            iv0[t] = sv;
            yv[t]  = expf(ylv[t]) + EPS;
        } else {
            int n = sub - 1;
            float a = -(expf(Dm[n * LD + t]) + EPS);
            unsigned short h = f2b(a);
            AbTh[t * NB + n] = h;
            AbTl[t * NB + n] = f2b(a - b2f(h));
        }
    } else if (bid < 641) {
        int i = (bid - 577) * 256 + tid;      // float4 index over 256*256/4
        float4 v = ((const float4*)Bw)[i];
        ((ushort4*)Bwh)[i] = make_ushort4(f2b(v.x), f2b(v.y), f2b(v.z), f2b(v.w));
    } else {
        int i = (bid - 641) * 256 + tid;      // float4 index over BT*LD/4
        float4 v = ((const float4*)Z)[i];
        ((ushort4*)Zh)[i] = make_ushort4(f2b(v.x), f2b(v.y), f2b(v.z), f2b(v.w));
    }
}

// ---------------------------------------------------------------------------
// k_zb: grid (BT/128, 3).
//  y<2 : alphas[:,y*128:(y+1)*128] = Zh @ Bwh^T   (fp32 out)
//  y==2: logits = Zh @ cwbh^T + cb                (fp32 out, N=32)
// ---------------------------------------------------------------------------
__global__ __launch_bounds__(256) void k_zb(const unsigned short* __restrict__ Zh,
                                            const unsigned short* __restrict__ Bwh,
                                            const unsigned short* __restrict__ cwbh,
                                            const float* __restrict__ cb,
                                            float* __restrict__ alphas,
                                            float* __restrict__ logits) {
    __shared__ unsigned short As[128 * 32];
    __shared__ unsigned short Bs[128 * 32];
    int tid = threadIdx.x, lane = tid & 63, wv = tid >> 6;
    int m0 = blockIdx.x * 128;
    int y  = blockIdx.y;
    if (y < 2) {
        int n0 = y * 128;
        int wm = (wv & 1) * 64, wn = (wv >> 1) * 64;
        f32x4 acc[4][4];
#pragma unroll
        for (int i = 0; i < 4; ++i)
#pragma unroll
            for (int j = 0; j < 4; ++j) acc[i][j] = (f32x4){0.f, 0.f, 0.f, 0.f};
        for (int kb = 0; kb < LD; kb += 32) {
            stage_tile(Zh, m0, LD, kb, As, wv, lane);
            stage_tile(Bwh, n0, LD, kb, Bs, wv, lane);
            __syncthreads();
            int qd = lane >> 4;
            bf16x8 af[4], bf[4];
#pragma unroll
            for (int i = 0; i < 4; ++i) af[i] = frag_ld(As, wm + i * 16 + (lane & 15), qd);
#pragma unroll
            for (int j = 0; j < 4; ++j) bf[j] = frag_ld(Bs, wn + j * 16 + (lane & 15), qd);
#pragma unroll
            for (int i = 0; i < 4; ++i)
#pragma unroll
                for (int j = 0; j < 4; ++j)
                    acc[i][j] = __builtin_amdgcn_mfma_f32_16x16x32_bf16(af[i], bf[j], acc[i][j], 0, 0, 0);
            __syncthreads();
        }
        int col = wn + (lane & 15);
        int rb  = wm + ((lane >> 4) << 2);
#pragma unroll
        for (int i = 0; i < 4; ++i)
#pragma unroll
            for (int j = 0; j < 4; ++j)
#pragma unroll
                for (int r = 0; r < 4; ++r)
                    alphas[(size_t)(m0 + rb + i * 16 + r) * LD + n0 + col + j * 16] = acc[i][j][r];
    } else {
        f32x4 acc[2][2];
#pragma unroll
        for (int i = 0; i < 2; ++i)
#pragma unroll
            for (int j = 0; j < 2; ++j) acc[i][j] = (f32x4){0.f, 0.f, 0.f, 0.f};
        for (int kb = 0; kb < LD; kb += 32) {
            stage_tile(Zh, m0, LD, kb, As, wv, lane);
            if (wv < 2) {
                int r = wv * 16 + (lane >> 2);
                int qd = (lane & 3) ^ ((r >> 1) & 3);
                gl_lds16(cwbh + (size_t)r * LD + kb + qd * 8, Bs + wv * 512);
            }
            __syncthreads();
            int qd = lane >> 4;
            bf16x8 af[2], bff[2];
#pragma unroll
            for (int i = 0; i < 2; ++i) af[i] = frag_ld(As, wv * 32 + i * 16 + (lane & 15), qd);
#pragma unroll
            for (int j = 0; j < 2; ++j) bff[j] = frag_ld(Bs, j * 16 + (lane & 15), qd);
#pragma unroll
            for (int i = 0; i < 2; ++i)
#pragma unroll
                for (int j = 0; j < 2; ++j)
                    acc[i][j] = __builtin_amdgcn_mfma_f32_16x16x32_bf16(af[i], bff[j], acc[i][j], 0, 0, 0);
            __syncthreads();
        }
        int col = lane & 15;
        int rb  = (lane >> 4) << 2;
#pragma unroll
        for (int i = 0; i < 2; ++i)
#pragma unroll
            for (int j = 0; j < 2; ++j)
#pragma unroll
                for (int r = 0; r < 4; ++r) {
                    int row = m0 + wv * 32 + i * 16 + rb + r;
                    int cc  = j * 16 + col;
                    logits[(size_t)row * NB + cc] = acc[i][j][r] + cb[cc];
                }
    }
}

// ---------------------------------------------------------------------------
// k_tot: chunk totals (R4-fast version, minus P writeback).
// ---------------------------------------------------------------------------
__global__ __launch_bounds__(256) void k_tot(const float* __restrict__ logits,
                                             const float* __restrict__ alphas,
                                             const float* __restrict__ obs,
                                             const unsigned short* __restrict__ AbTh,
                                             const unsigned short* __restrict__ AbTl,
                                             float* __restrict__ totA,
                                             float* __restrict__ totBm,
                                             float* __restrict__ totBv) {
    __shared__ unsigned int U[8192];
    __shared__ unsigned short Ph[1024];
    __shared__ unsigned short Pl[1024];
    int tid = threadIdx.x;
    int d = tid;
    int bid = xcd_map(blockIdx.x);
    int bt0 = bid * CHUNK;

    // early prefetch: all 32 alphas for this column
    float av[32];
#pragma unroll
    for (int i = 0; i < 32; ++i) av[i] = alphas[(size_t)(bt0 + i) * LD + d];

    // softmax -> Ph/Pl (swizzled)
    int l = tid & 31, rg = tid >> 5;
#pragma unroll
    for (int jj = 0; jj < 4; ++jj) {
        int row = rg * 4 + jj;
        float v = logits[(size_t)(bt0 + row) * NB + l];
        float mx = v;
#pragma unroll
        for (int off = 16; off >= 1; off >>= 1) mx = fmaxf(mx, __shfl_xor(mx, off, 32));
        float e = __expf(v - mx);
        float s = e;
#pragma unroll
        for (int off = 16; off >= 1; off >>= 1) s += __shfl_xor(s, off, 32);
        float p = e * __builtin_amdgcn_rcpf(s);
        unsigned short h = f2b(p);
        unsigned short lo = f2b(p - b2f(h));
        int sa = row * 32 + ((((l >> 3) ^ ((row >> 1) & 3))) << 3) + (l & 7);
        Ph[sa] = h;
        Pl[sa] = lo;
    }
    __syncthreads();

    // Am = P @ AbT^T (3-term hi/lo) -> U (fp32)
    int lane = tid & 63, wv = tid >> 6;
    int qd = lane >> 4, mr = lane & 15;
    bf16x8 ph[2], pl[2];
#pragma unroll
    for (int iT = 0; iT < 2; ++iT) {
        ph[iT] = frag_ld(Ph, iT * 16 + mr, qd);
        pl[iT] = frag_ld(Pl, iT * 16 + mr, qd);
    }
#pragma unroll
    for (int j = 0; j < 4; ++j) {
        int dcol = wv * 64 + j * 16 + mr;
        bf16x8 ah = *(const bf16x8*)(AbTh + dcol * NB + qd * 8);
        bf16x8 al = *(const bf16x8*)(AbTl + dcol * NB + qd * 8);
#pragma unroll
        for (int iT = 0; iT < 2; ++iT) {
            f32x4 acc = (f32x4){0.f, 0.f, 0.f, 0.f};
            acc = __builtin_amdgcn_mfma_f32_16x16x32_bf16(ph[iT], ah, acc, 0, 0, 0);
            acc = __builtin_amdgcn_mfma_f32_16x16x32_bf16(pl[iT], ah, acc, 0, 0, 0);
            acc = __builtin_amdgcn_mfma_f32_16x16x32_bf16(ph[iT], al, acc, 0, 0, 0);
#pragma unroll
            for (int r = 0; r < 4; ++r)
                U[u_idx(iT * 16 + qd * 4 + r, dcol)] = __float_as_uint(acc[r]);
        }
    }
    __syncthreads();

    // scan
    float ra = 1.f, rm = 0.f, rv = 0.f;
    int ubase = ((d >> 5) << 10) + (d & 7);
    int qb = (d >> 3) & 3;
#pragma unroll
    for (int i = 0; i < CHUNK; ++i) {
        int ui = ubase + (i << 5) + ((qb ^ (i & 3)) << 3);
        float Am = __uint_as_float(U[ui]);
        float tt = obs[bt0 + i];
        float eAm = __expf(Am * tt);
        float ieA = __builtin_amdgcn_rcpf(Am);
        float e2  = eAm * eAm;
        float eBm = (eAm - 1.f) * ieA * av[i];
        float eBv = fmaf(0.5f * (e2 - 1.f), ieA, EPS);
        rm = fmaf(eAm, rm, eBm);
        rv = fmaf(e2, rv, eBv);
        ra *= eAm;
    }
    int pidx = bid * LD + d;
    totA[pidx] = ra; totBm[pidx] = rm; totBv[pidx] = rv;
}

// exclusive prefix over chunks per (b,d), batched loads (8 ahead)
__global__ __launch_bounds__(256) void k_chunkpfx(const float* __restrict__ totA,
                                                  const float* __restrict__ totBm,
                                                  const float* __restrict__ totBv,
                                                  float* __restrict__ preA,
                                                  float* __restrict__ preBm,
                                                  float* __restrict__ preBv) {
    int d = threadIdx.x;
    int b = blockIdx.x;
    float Pa = 1.f, Pm = 0.f, Pv = 0.f;
    for (int g = 0; g < 8; ++g) {
        float a8[8], m8[8], v8[8];
#pragma unroll
        for (int k = 0; k < 8; ++k) {
            int pidx = (b * NCH + g * 8 + k) * LD + d;
            a8[k] = totA[pidx]; m8[k] = totBm[pidx]; v8[k] = totBv[pidx];
        }
#pragma unroll
        for (int k = 0; k < 8; ++k) {
            int pidx = (b * NCH + g * 8 + k) * LD + d;
            preA[pidx] = Pa; preBm[pidx] = Pm; preBv[pidx] = Pv;
            Pm = fmaf(a8[k], Pm, m8[k]);
            Pv = fmaf(a8[k] * a8[k], Pv, v8[k]);
            Pa *= a8[k];
        }
    }
}

// ---------------------------------------------------------------------------
// k_sms: R2-verified structure + fast-math only.
//   softmax from fp32 logits -> Ph/Pl LDS -> Am MFMA -> U -> scan (av batched
//   in-loop, obs from LDS) -> barrier-free MFMA GEMM phase.
// LDS: U 32KB | Ph/Pl 4KB | obs 128B.
// ---------------------------------------------------------------------------
__global__ __launch_bounds__(256) void k_sms(const float* __restrict__ logits,
                                             const float* __restrict__ alphas,
                                             const float* __restrict__ obs,
                                             const unsigned short* __restrict__ AbTh,
                                             const unsigned short* __restrict__ AbTl,
                                             const float* __restrict__ preA,
                                             const float* __restrict__ preBm,
                                             const float* __restrict__ preBv,
                                             const float* __restrict__ im0,
                                             const float* __restrict__ iv0,
                                             const float* __restrict__ yv,
                                             const unsigned short* __restrict__ Zh,
                                             const unsigned short* __restrict__ GMh,
                                             const unsigned short* __restrict__ GCh,
                                             float* __restrict__ means,
                                             float* __restrict__ stds) {
    __shared__ unsigned int U[8192];
    __shared__ unsigned short Ph[1024];
    __shared__ unsigned short Pl[1024];
    __shared__ float obs_s[CHUNK];
    int tid = threadIdx.x, lane = tid & 63, wv = tid >> 6;
    int d = tid;
    int bt0 = blockIdx.x * CHUNK;

    // softmax -> Ph/Pl (swizzled); obs -> LDS
    if (tid < CHUNK) obs_s[tid] = obs[bt0 + tid];
    int l = tid & 31, rg = tid >> 5;
#pragma unroll
    for (int jj = 0; jj < 4; ++jj) {
        int row = rg * 4 + jj;
        float v = logits[(size_t)(bt0 + row) * NB + l];
        float mx = v;
#pragma unroll
        for (int off = 16; off >= 1; off >>= 1) mx = fmaxf(mx, __shfl_xor(mx, off, 32));
        float e = __expf(v - mx);
        float s = e;
#pragma unroll
        for (int off = 16; off >= 1; off >>= 1) s += __shfl_xor(s, off, 32);
        float p = e * __builtin_amdgcn_rcpf(s);
        unsigned short h = f2b(p);
        unsigned short lo = f2b(p - b2f(h));
        int sa = row * 32 + ((((l >> 3) ^ ((row >> 1) & 3))) << 3) + (l & 7);
        Ph[sa] = h;
        Pl[sa] = lo;
    }
    __syncthreads();

    // Am = P @ AbT^T (3-term hi/lo) -> U (fp32)
    int qd = lane >> 4, mr = lane & 15;
    bf16x8 ph[2], pl[2];
#pragma unroll
    for (int iT = 0; iT < 2; ++iT) {
        ph[iT] = frag_ld(Ph, iT * 16 + mr, qd);
        pl[iT] = frag_ld(Pl, iT * 16 + mr, qd);
    }
#pragma unroll
    for (int j = 0; j < 4; ++j) {
        int dcol = wv * 64 + j * 16 + mr;
        bf16x8 ah = *(const bf16x8*)(AbTh + dcol * NB + qd * 8);
        bf16x8 al = *(const bf16x8*)(AbTl + dcol * NB + qd * 8);
#pragma unroll
        for (int iT = 0; iT < 2; ++iT) {
            f32x4 acc = (f32x4){0.f, 0.f, 0.f, 0.f};
            acc = __builtin_amdgcn_mfma_f32_16x16x32_bf16(ph[iT], ah, acc, 0, 0, 0);
            acc = __builtin_amdgcn_mfma_f32_16x16x32_bf16(pl[iT], ah, acc, 0, 0, 0);
            acc = __builtin_amdgcn_mfma_f32_16x16x32_bf16(ph[iT], al, acc, 0, 0, 0);
#pragma unroll
            for (int r = 0; r < 4; ++r)
                U[u_idx(iT * 16 + qd * 4 + r, dcol)] = __float_as_uint(acc[r]);
        }
    }
    __syncthreads();

    // carry-ins (after prolog, as in R2)
    int pidx = blockIdx.x * LD + d;
    float ga = preA[pidx], gm = preBm[pidx], gv = preBv[pidx];
    float i0 = im0[d], v0 = iv0[d], yvd = yv[d];

    // scan: av batched 8-at-a-time in-loop (overlaps with compute)
    int ubase = ((d >> 5) << 10) + (d & 7);
    int qb = (d >> 3) & 3;
    for (int g = 0; g < 4; ++g) {
        float av[8];
#pragma unroll
        for (int k = 0; k < 8; ++k)
            av[k] = alphas[(size_t)(bt0 + g * 8 + k) * LD + d];
#pragma unroll
        for (int k = 0; k < 8; ++k) {
            int i = g * 8 + k;
            int ui = ubase + (i << 5) + ((qb ^ (i & 3)) << 3);
            float Am = __uint_as_float(U[ui]);
            float tt = obs_s[i];
            float eAm = __expf(Am * tt);
            float ieA = __builtin_amdgcn_rcpf(Am);
            float e2  = eAm * eAm;
            float eBm = (eAm - 1.f) * ieA * av[k];
            float eBv = fmaf(0.5f * (e2 - 1.f), ieA, EPS);
            gm = fmaf(eAm, gm, eBm);
            gv = fmaf(e2, gv, eBv);
            ga *= eAm;
            float mm = fmaf(ga, i0, gm);
            float vv = fmaf(ga * ga, v0, gv) + yvd;
            float ss = sqrtf(vv);
            U[ui] = ((unsigned int)f2b(mm) << 16) | (unsigned int)f2b(ss);
        }
    }
    __syncthreads();

    // ---- barrier-free MFMA GEMM phase ----
    f32x4 accm[2][4], accs[2][4];
#pragma unroll
    for (int iT = 0; iT < 2; ++iT)
#pragma unroll
        for (int j = 0; j < 4; ++j) {
            accm[iT][j] = (f32x4){0.f, 0.f, 0.f, 0.f};
            accs[iT][j] = (f32x4){0.f, 0.f, 0.f, 0.f};
        }
    for (int kc = 0; kc < 8; ++kc) {
        bf16x8 am[2], asv[2], az[2];
#pragma unroll
        for (int iT = 0; iT < 2; ++iT) {
            int row = iT * 16 + mr;
            int off = (kc << 10) + (row << 5) + ((qd ^ (row & 3)) << 3);
            uint4 ua = *(const uint4*)(U + off);
            uint4 ub = *(const uint4*)(U + off + 4);
            unsigned int uu[8] = {ua.x, ua.y, ua.z, ua.w, ub.x, ub.y, ub.z, ub.w};
            bf16x8 m_, s_;
#pragma unroll
            for (int k = 0; k < 8; ++k) {
                m_[k] = (short)(uu[k] >> 16);
                s_[k] = (short)(uu[k] & 0xffffu);
            }
            am[iT] = m_; asv[iT] = s_;
            az[iT] = *(const bf16x8*)(Zh + (size_t)(bt0 + row) * LD + kc * 32 + qd * 8);
        }
#pragma unroll
        for (int j = 0; j < 4; ++j) {
            int brow = wv * 64 + j * 16 + mr;
            bf16x8 bm = *(const bf16x8*)(GMh + (size_t)brow * LD + kc * 32 + qd * 8);
            bf16x8 bc = *(const bf16x8*)(GCh + (size_t)brow * LD + kc * 32 + qd * 8);
#pragma unroll
            for (int iT = 0; iT < 2; ++iT) {
                accm[iT][j] = __builtin_amdgcn_mfma_f32_16x16x32_bf16(am[iT],  bm, accm[iT][j], 0, 0, 0);
                accs[iT][j] = __builtin_amdgcn_mfma_f32_16x16x32_bf16(asv[iT], bm, accs[iT][j], 0, 0, 0);
                accm[iT][j] = __builtin_amdgcn_mfma_f32_16x16x32_bf16(az[iT],  bc, accm[iT][j], 0, 0, 0);
            }
        }
    }

    // ---- epilogue ----
    int col0 = wv * 64 + mr;
    int rb   = (lane >> 4) << 2;
#pragma unroll
    for (int i = 0; i < 2; ++i)
#pragma unroll
        for (int j = 0; j < 4; ++j)
#pragma unroll
            for (int r = 0; r < 4; ++r) {
                size_t off = (size_t)(bt0 + i * 16 + rb + r) * LD + col0 + j * 16;
                means[off] = accm[i][j][r];
                stds[off]  = accs[i][j][r];
            }
}

// ---------------------------------------------------------------------------
extern "C" void kernel_launch(void* const* d_in, const int* in_sizes, int n_in,
                              void* d_out, int out_size, void* d_ws, size_t ws_size,
                              hipStream_t stream) {
    const float* Z   = (const float*)d_in[0];
    const float* obs = (const float*)d_in[1];
    const float* Dm  = (const float*)d_in[2];
    const float* cw  = (const float*)d_in[3];
    const float* cb  = (const float*)d_in[4];
    const float* Ew  = (const float*)d_in[5];
    const float* Bw  = (const float*)d_in[6];
    const float* Cw  = (const float*)d_in[7];
    const float* Mw  = (const float*)d_in[8];
    const float* imp = (const float*)d_in[9];
    const float* ilv = (const float*)d_in[10];
    const float* ylv = (const float*)d_in[11];

    float* out    = (float*)d_out;
    float* means  = out;
    float* stds   = out + (size_t)BT * LD;
    float* alphas = out + (size_t)2 * BT * LD;

    char* ws = (char*)d_ws;
    size_t o = 0;
    unsigned short* Zh   = (unsigned short*)(ws + o); o += (size_t)BT * LD * 2;   // 16MB
    float*          logits=(float*)(ws + o);          o += (size_t)BT * NB * 4;   // 4MB
    unsigned short* GMh  = (unsigned short*)(ws + o); o += (size_t)LD * LD * 2;
    unsigned short* GCh  = (unsigned short*)(ws + o); o += (size_t)LD * LD * 2;
    unsigned short* Bwh  = (unsigned short*)(ws + o); o += (size_t)LD * LD * 2;
    unsigned short* cwbh = (unsigned short*)(ws + o); o += (size_t)NB * LD * 2;
    unsigned short* AbTh = (unsigned short*)(ws + o); o += (size_t)LD * NB * 2;
    unsigned short* AbTl = (unsigned short*)(ws + o); o += (size_t)LD * NB * 2;
    float* totA  = (float*)(ws + o); o += (size_t)B_ * NCH * LD * 4;
    float* totBm = (float*)(ws + o); o += (size_t)B_ * NCH * LD * 4;
    float* totBv = (float*)(ws + o); o += (size_t)B_ * NCH * LD * 4;
    float* preA  = (float*)(ws + o); o += (size_t)B_ * NCH * LD * 4;
    float* preBm = (float*)(ws + o); o += (size_t)B_ * NCH * LD * 4;
    float* preBv = (float*)(ws + o); o += (size_t)B_ * NCH * LD * 4;
    float* im0   = (float*)(ws + o); o += LD * 4;
    float* iv0   = (float*)(ws + o); o += LD * 4;
    float* yv    = (float*)(ws + o); o += LD * 4;

    // 1. all precompute
    k_pre<<<dim3(641 + BT * LD / 1024), dim3(256), 0, stream>>>(
        Z, Dm, cw, Ew, Bw, Cw, Mw, imp, ilv, ylv,
        GMh, GCh, cwbh, im0, iv0, yv, AbTh, AbTl, Bwh, Zh);

    // 2. alphas + logits (both straight from Zh)
    k_zb<<<dim3(BT / 128, 3), dim3(256), 0, stream>>>(Zh, Bwh, cwbh, cb, alphas, logits);

    // 3-4. chunk totals + prefix
    k_tot<<<dim3(B_ * NCH), dim3(256), 0, stream>>>(logits, alphas, obs, AbTh, AbTl,
                                                    totA, totBm, totBv);
    k_chunkpfx<<<dim3(B_), dim3(LD), 0, stream>>>(totA, totBm, totBv, preA, preBm, preBv);

    // 5. fused scan + means/stds GEMMs
    k_sms<<<dim3(B_ * NCH), dim3(256), 0, stream>>>(logits, alphas, obs, AbTh, AbTl,
                                                    preA, preBm, preBv,
                                                    im0, iv0, yv,
                                                    Zh, GMh, GCh, means, stds);
}

// Round 7
// 234.460 us; speedup vs baseline: 1.0396x; 1.0050x over previous
//
#include <hip/hip_runtime.h>
#include <math.h>

#define EPS 1e-6f

#define B_   16
#define T_   2048
#define LD   256
#define NB   32
#define BT   (B_ * T_)          // 32768
#define NCH  64
#define CHUNK (T_ / NCH)        // 32

typedef short bf16x8 __attribute__((ext_vector_type(8)));
typedef float f32x4  __attribute__((ext_vector_type(4)));

__device__ __forceinline__ unsigned short f2b(float f) {
    unsigned int u = __float_as_uint(f);
    unsigned int r = (u + 0x7fffu + ((u >> 16) & 1u)) >> 16;
    return (unsigned short)r;
}

__device__ __forceinline__ float b2f(unsigned short h) {
    return __uint_as_float(((unsigned int)h) << 16);
}

__device__ __forceinline__ void gl_lds16(const void* g, void* l) {
    __builtin_amdgcn_global_load_lds(
        (const __attribute__((address_space(1))) unsigned int*)g,
        (__attribute__((address_space(3))) unsigned int*)l, 16, 0, 0);
}

// XCD-align map (k_tot only): hardware block wg (XCD = wg&7) -> work j with
// (j>>2)&7 == wg&7.  Bijective on [0,1024).
__device__ __forceinline__ int xcd_map(int wg) {
    int x = wg & 7, s = wg >> 3;
    return (s & 3) | (x << 2) | ((s >> 2) << 5);
}

// Stage a 128-row x 32-col bf16 tile into LDS [128][32] with quad swizzle:
// physical quad p at row r holds logical quad qd = p ^ ((r>>1)&3).
__device__ __forceinline__ void stage_tile(const unsigned short* __restrict__ src,
                                           int row0, int stride, int kb,
                                           unsigned short* lds, int wv, int lane) {
#pragma unroll
    for (int cc = 0; cc < 2; ++cc) {
        int c = wv * 2 + cc;                 // chunk 0..7, 16 rows each
        int r = c * 16 + (lane >> 2);
        int qd = (lane & 3) ^ ((r >> 1) & 3);
        const unsigned short* g = src + (size_t)(row0 + r) * stride + kb + qd * 8;
        gl_lds16(g, lds + c * 512);          // wave-uniform LDS base; HW adds lane*16B
    }
}

__device__ __forceinline__ bf16x8 frag_ld(const unsigned short* lds, int row, int qd) {
    int pq = qd ^ ((row >> 1) & 3);
    return *(const bf16x8*)(lds + row * 32 + pq * 8);
}

// U buffer chunk: [8 dc][32 i][32 dj] uint32, quad-swizzled within each 128B row:
// physical 8-uint quad p = (dj>>3) ^ (i&3).
__device__ __forceinline__ int u_idx(int i, int d) {
    return ((d >> 5) << 10) + (i << 5) + (((((d >> 3) & 3)) ^ (i & 3)) << 3) + (d & 7);
}

// ---------------------------------------------------------------------------
// k_pre: ALL precompute in one launch, decoded by blockIdx.x (256 thr/block).
// ---------------------------------------------------------------------------
__global__ __launch_bounds__(256) void k_pre(const float* __restrict__ Z,
                                             const float* __restrict__ Dm,
                                             const float* __restrict__ cw,
                                             const float* __restrict__ Ew,
                                             const float* __restrict__ Bw,
                                             const float* __restrict__ Cw,
                                             const float* __restrict__ Mw,
                                             const float* __restrict__ imp,
                                             const float* __restrict__ ilv,
                                             const float* __restrict__ ylv,
                                             unsigned short* __restrict__ GMh,
                                             unsigned short* __restrict__ GCh,
                                             unsigned short* __restrict__ cwbh,
                                             float* __restrict__ im0,
                                             float* __restrict__ iv0,
                                             float* __restrict__ yv,
                                             unsigned short* __restrict__ AbTh,
                                             unsigned short* __restrict__ AbTl,
                                             unsigned short* __restrict__ Bwh,
                                             unsigned short* __restrict__ Zh) {
    int bid = blockIdx.x;
    int tid = threadIdx.x;
    if (bid < 544) {
        // small GEMM: out[f][d] = sum_e W[f][e] * E[e][d]
        const float* W; const float* E; unsigned short* out; int d0, f0;
        if (bid < 256)      { W = Mw; E = Ew; out = GMh;  d0 = (bid & 15) * 16; f0 = (bid >> 4) * 16; }
        else if (bid < 512) { W = Cw; E = Ew; out = GCh;  d0 = (bid & 15) * 16; f0 = ((bid - 256) >> 4) * 16; }
        else                { W = cw; E = Bw; out = cwbh; d0 = (bid & 15) * 16; f0 = ((bid - 512) >> 4) * 16; }
        __shared__ float Ws[16][17];
        __shared__ float Es[16][17];
        int tx = tid & 15, ty = tid >> 4;
        float acc = 0.f;
        for (int eb = 0; eb < LD; eb += 16) {
            Ws[ty][tx] = W[(f0 + ty) * LD + eb + tx];
            Es[ty][tx] = E[(eb + ty) * LD + d0 + tx];
            __syncthreads();
#pragma unroll
            for (int k = 0; k < 16; ++k) acc = fmaf(Ws[ty][k], Es[k][tx], acc);
            __syncthreads();
        }
        out[(f0 + ty) * LD + d0 + tx] = f2b(acc);
    } else if (bid < 577) {
        int sub = bid - 544;
        int t = tid;
        if (sub == 0) {
            float sm = 0.f, sv = 0.f;
            for (int k = 0; k < LD; ++k) {
                float e = Ew[k * LD + t];
                sm = fmaf(e, imp[k], sm);
                sv = fmaf(e * e, expf(ilv[k]) + EPS, sv);
            }
            im0[t] = sm;
            iv0[t] = sv;
            yv[t]  = expf(ylv[t]) + EPS;
        } else {
            int n = sub - 1;
            float a = -(expf(Dm[n * LD + t]) + EPS);
            unsigned short h = f2b(a);
            AbTh[t * NB + n] = h;
            AbTl[t * NB + n] = f2b(a - b2f(h));
        }
    } else if (bid < 641) {
        int i = (bid - 577) * 256 + tid;      // float4 index over 256*256/4
        float4 v = ((const float4*)Bw)[i];
        ((ushort4*)Bwh)[i] = make_ushort4(f2b(v.x), f2b(v.y), f2b(v.z), f2b(v.w));
    } else {
        int i = (bid - 641) * 256 + tid;      // float4 index over BT*LD/4
        float4 v = ((const float4*)Z)[i];
        ((ushort4*)Zh)[i] = make_ushort4(f2b(v.x), f2b(v.y), f2b(v.z), f2b(v.w));
    }
}

// ---------------------------------------------------------------------------
// k_zb: grid (BT/128, 3).
//  y<2 : alphas[:,y*128:(y+1)*128] = Zh @ Bwh^T   (fp32 out)
//  y==2: logits = Zh @ cwbh^T + cb                (fp32 out, N=32)
// ---------------------------------------------------------------------------
__global__ __launch_bounds__(256) void k_zb(const unsigned short* __restrict__ Zh,
                                            const unsigned short* __restrict__ Bwh,
                                            const unsigned short* __restrict__ cwbh,
                                            const float* __restrict__ cb,
                                            float* __restrict__ alphas,
                                            float* __restrict__ logits) {
    __shared__ unsigned short As[128 * 32];
    __shared__ unsigned short Bs[128 * 32];
    int tid = threadIdx.x, lane = tid & 63, wv = tid >> 6;
    int m0 = blockIdx.x * 128;
    int y  = blockIdx.y;
    if (y < 2) {
        int n0 = y * 128;
        int wm = (wv & 1) * 64, wn = (wv >> 1) * 64;
        f32x4 acc[4][4];
#pragma unroll
        for (int i = 0; i < 4; ++i)
#pragma unroll
            for (int j = 0; j < 4; ++j) acc[i][j] = (f32x4){0.f, 0.f, 0.f, 0.f};
        for (int kb = 0; kb < LD; kb += 32) {
            stage_tile(Zh, m0, LD, kb, As, wv, lane);
            stage_tile(Bwh, n0, LD, kb, Bs, wv, lane);
            __syncthreads();
            int qd = lane >> 4;
            bf16x8 af[4], bf[4];
#pragma unroll
            for (int i = 0; i < 4; ++i) af[i] = frag_ld(As, wm + i * 16 + (lane & 15), qd);
#pragma unroll
            for (int j = 0; j < 4; ++j) bf[j] = frag_ld(Bs, wn + j * 16 + (lane & 15), qd);
#pragma unroll
            for (int i = 0; i < 4; ++i)
#pragma unroll
                for (int j = 0; j < 4; ++j)
                    acc[i][j] = __builtin_amdgcn_mfma_f32_16x16x32_bf16(af[i], bf[j], acc[i][j], 0, 0, 0);
            __syncthreads();
        }
        int col = wn + (lane & 15);
        int rb  = wm + ((lane >> 4) << 2);
#pragma unroll
        for (int i = 0; i < 4; ++i)
#pragma unroll
            for (int j = 0; j < 4; ++j)
#pragma unroll
                for (int r = 0; r < 4; ++r)
                    alphas[(size_t)(m0 + rb + i * 16 + r) * LD + n0 + col + j * 16] = acc[i][j][r];
    } else {
        f32x4 acc[2][2];
#pragma unroll
        for (int i = 0; i < 2; ++i)
#pragma unroll
            for (int j = 0; j < 2; ++j) acc[i][j] = (f32x4){0.f, 0.f, 0.f, 0.f};
        for (int kb = 0; kb < LD; kb += 32) {
            stage_tile(Zh, m0, LD, kb, As, wv, lane);
            if (wv < 2) {
                int r = wv * 16 + (lane >> 2);
                int qd = (lane & 3) ^ ((r >> 1) & 3);
                gl_lds16(cwbh + (size_t)r * LD + kb + qd * 8, Bs + wv * 512);
            }
            __syncthreads();
            int qd = lane >> 4;
            bf16x8 af[2], bff[2];
#pragma unroll
            for (int i = 0; i < 2; ++i) af[i] = frag_ld(As, wv * 32 + i * 16 + (lane & 15), qd);
#pragma unroll
            for (int j = 0; j < 2; ++j) bff[j] = frag_ld(Bs, j * 16 + (lane & 15), qd);
#pragma unroll
            for (int i = 0; i < 2; ++i)
#pragma unroll
                for (int j = 0; j < 2; ++j)
                    acc[i][j] = __builtin_amdgcn_mfma_f32_16x16x32_bf16(af[i], bff[j], acc[i][j], 0, 0, 0);
            __syncthreads();
        }
        int col = lane & 15;
        int rb  = (lane >> 4) << 2;
#pragma unroll
        for (int i = 0; i < 2; ++i)
#pragma unroll
            for (int j = 0; j < 2; ++j)
#pragma unroll
                for (int r = 0; r < 4; ++r) {
                    int row = m0 + wv * 32 + i * 16 + rb + r;
                    int cc  = j * 16 + col;
                    logits[(size_t)row * NB + cc] = acc[i][j][r] + cb[cc];
                }
    }
}

// ---------------------------------------------------------------------------
// k_tot: chunk totals (R6 proven-fast version, unchanged).
// ---------------------------------------------------------------------------
__global__ __launch_bounds__(256) void k_tot(const float* __restrict__ logits,
                                             const float* __restrict__ alphas,
                                             const float* __restrict__ obs,
                                             const unsigned short* __restrict__ AbTh,
                                             const unsigned short* __restrict__ AbTl,
                                             float* __restrict__ totA,
                                             float* __restrict__ totBm,
                                             float* __restrict__ totBv) {
    __shared__ unsigned int U[8192];
    __shared__ unsigned short Ph[1024];
    __shared__ unsigned short Pl[1024];
    int tid = threadIdx.x;
    int d = tid;
    int bid = xcd_map(blockIdx.x);
    int bt0 = bid * CHUNK;

    // early prefetch: all 32 alphas for this column
    float av[32];
#pragma unroll
    for (int i = 0; i < 32; ++i) av[i] = alphas[(size_t)(bt0 + i) * LD + d];

    // softmax -> Ph/Pl (swizzled)
    int l = tid & 31, rg = tid >> 5;
#pragma unroll
    for (int jj = 0; jj < 4; ++jj) {
        int row = rg * 4 + jj;
        float v = logits[(size_t)(bt0 + row) * NB + l];
        float mx = v;
#pragma unroll
        for (int off = 16; off >= 1; off >>= 1) mx = fmaxf(mx, __shfl_xor(mx, off, 32));
        float e = __expf(v - mx);
        float s = e;
#pragma unroll
        for (int off = 16; off >= 1; off >>= 1) s += __shfl_xor(s, off, 32);
        float p = e * __builtin_amdgcn_rcpf(s);
        unsigned short h = f2b(p);
        unsigned short lo = f2b(p - b2f(h));
        int sa = row * 32 + ((((l >> 3) ^ ((row >> 1) & 3))) << 3) + (l & 7);
        Ph[sa] = h;
        Pl[sa] = lo;
    }
    __syncthreads();

    // Am = P @ AbT^T (3-term hi/lo) -> U (fp32)
    int lane = tid & 63, wv = tid >> 6;
    int qd = lane >> 4, mr = lane & 15;
    bf16x8 ph[2], pl[2];
#pragma unroll
    for (int iT = 0; iT < 2; ++iT) {
        ph[iT] = frag_ld(Ph, iT * 16 + mr, qd);
        pl[iT] = frag_ld(Pl, iT * 16 + mr, qd);
    }
#pragma unroll
    for (int j = 0; j < 4; ++j) {
        int dcol = wv * 64 + j * 16 + mr;
        bf16x8 ah = *(const bf16x8*)(AbTh + dcol * NB + qd * 8);
        bf16x8 al = *(const bf16x8*)(AbTl + dcol * NB + qd * 8);
#pragma unroll
        for (int iT = 0; iT < 2; ++iT) {
            f32x4 acc = (f32x4){0.f, 0.f, 0.f, 0.f};
            acc = __builtin_amdgcn_mfma_f32_16x16x32_bf16(ph[iT], ah, acc, 0, 0, 0);
            acc = __builtin_amdgcn_mfma_f32_16x16x32_bf16(pl[iT], ah, acc, 0, 0, 0);
            acc = __builtin_amdgcn_mfma_f32_16x16x32_bf16(ph[iT], al, acc, 0, 0, 0);
#pragma unroll
            for (int r = 0; r < 4; ++r)
                U[u_idx(iT * 16 + qd * 4 + r, dcol)] = __float_as_uint(acc[r]);
        }
    }
    __syncthreads();

    // scan
    float ra = 1.f, rm = 0.f, rv = 0.f;
    int ubase = ((d >> 5) << 10) + (d & 7);
    int qb = (d >> 3) & 3;
#pragma unroll
    for (int i = 0; i < CHUNK; ++i) {
        int ui = ubase + (i << 5) + ((qb ^ (i & 3)) << 3);
        float Am = __uint_as_float(U[ui]);
        float tt = obs[bt0 + i];
        float eAm = __expf(Am * tt);
        float ieA = __builtin_amdgcn_rcpf(Am);
        float e2  = eAm * eAm;
        float eBm = (eAm - 1.f) * ieA * av[i];
        float eBv = fmaf(0.5f * (e2 - 1.f), ieA, EPS);
        rm = fmaf(eAm, rm, eBm);
        rv = fmaf(e2, rv, eBv);
        ra *= eAm;
    }
    int pidx = bid * LD + d;
    totA[pidx] = ra; totBm[pidx] = rm; totBv[pidx] = rv;
}

// exclusive prefix over chunks per (b,d), batched loads (8 ahead)
__global__ __launch_bounds__(256) void k_chunkpfx(const float* __restrict__ totA,
                                                  const float* __restrict__ totBm,
                                                  const float* __restrict__ totBv,
                                                  float* __restrict__ preA,
                                                  float* __restrict__ preBm,
                                                  float* __restrict__ preBv) {
    int d = threadIdx.x;
    int b = blockIdx.x;
    float Pa = 1.f, Pm = 0.f, Pv = 0.f;
    for (int g = 0; g < 8; ++g) {
        float a8[8], m8[8], v8[8];
#pragma unroll
        for (int k = 0; k < 8; ++k) {
            int pidx = (b * NCH + g * 8 + k) * LD + d;
            a8[k] = totA[pidx]; m8[k] = totBm[pidx]; v8[k] = totBv[pidx];
        }
#pragma unroll
        for (int k = 0; k < 8; ++k) {
            int pidx = (b * NCH + g * 8 + k) * LD + d;
            preA[pidx] = Pa; preBm[pidx] = Pm; preBv[pidx] = Pv;
            Pm = fmaf(a8[k], Pm, m8[k]);
            Pv = fmaf(a8[k] * a8[k], Pv, v8[k]);
            Pa *= a8[k];
        }
    }
}

// ---------------------------------------------------------------------------
// k_sms: one block = TWO chunks (64 rows).  softmax(64 rows) -> Am MFMA M=64
// -> two independent interleaved 32-step scan chains -> GEMM M=64 (B loads
// amortized 2x vs M=32).  Ph/Pl alias the U buffer (P is register-resident
// before any U write; extra barrier guards the alias).
// LDS: U 64KB total.
// ---------------------------------------------------------------------------
__global__ __launch_bounds__(256) void k_sms(const float* __restrict__ logits,
                                             const float* __restrict__ alphas,
                                             const float* __restrict__ obs,
                                             const unsigned short* __restrict__ AbTh,
                                             const unsigned short* __restrict__ AbTl,
                                             const float* __restrict__ preA,
                                             const float* __restrict__ preBm,
                                             const float* __restrict__ preBv,
                                             const float* __restrict__ im0,
                                             const float* __restrict__ iv0,
                                             const float* __restrict__ yv,
                                             const unsigned short* __restrict__ Zh,
                                             const unsigned short* __restrict__ GMh,
                                             const unsigned short* __restrict__ GCh,
                                             float* __restrict__ means,
                                             float* __restrict__ stds) {
    __shared__ unsigned int U[16384];                 // 64KB: [2 chunks][8 dc][32 i][32 dj]
    unsigned short* Ph = (unsigned short*)U;          // alias: 4KB
    unsigned short* Pl = (unsigned short*)(U + 1024); // alias: next 4KB
    int tid = threadIdx.x, lane = tid & 63, wv = tid >> 6;
    int d = tid;
    int bt0 = blockIdx.x * 64;

    // softmax over 64 rows -> Ph/Pl (swizzled)
    int l = tid & 31, rg = tid >> 5;
#pragma unroll
    for (int jj = 0; jj < 8; ++jj) {
        int row = rg * 8 + jj;
        float v = logits[(size_t)(bt0 + row) * NB + l];
        float mx = v;
#pragma unroll
        for (int off = 16; off >= 1; off >>= 1) mx = fmaxf(mx, __shfl_xor(mx, off, 32));
        float e = __expf(v - mx);
        float s = e;
#pragma unroll
        for (int off = 16; off >= 1; off >>= 1) s += __shfl_xor(s, off, 32);
        float p = e * __builtin_amdgcn_rcpf(s);
        unsigned short h = f2b(p);
        unsigned short lo = f2b(p - b2f(h));
        int sa = row * 32 + ((((l >> 3) ^ ((row >> 1) & 3))) << 3) + (l & 7);
        Ph[sa] = h;
        Pl[sa] = lo;
    }
    __syncthreads();

    // P fragments to registers (all of P) -- then barrier so U writes may alias
    int qd = lane >> 4, mr = lane & 15;
    bf16x8 ph[4], pl[4];
#pragma unroll
    for (int iT = 0; iT < 4; ++iT) {
        ph[iT] = frag_ld(Ph, iT * 16 + mr, qd);
        pl[iT] = frag_ld(Pl, iT * 16 + mr, qd);
    }
    __syncthreads();

    // Am = P @ AbT^T (3-term hi/lo), M=64 -> U (fp32)
#pragma unroll
    for (int j = 0; j < 4; ++j) {
        int dcol = wv * 64 + j * 16 + mr;
        bf16x8 ah = *(const bf16x8*)(AbTh + dcol * NB + qd * 8);
        bf16x8 al = *(const bf16x8*)(AbTl + dcol * NB + qd * 8);
#pragma unroll
        for (int iT = 0; iT < 4; ++iT) {
            f32x4 acc = (f32x4){0.f, 0.f, 0.f, 0.f};
            acc = __builtin_amdgcn_mfma_f32_16x16x32_bf16(ph[iT], ah, acc, 0, 0, 0);
            acc = __builtin_amdgcn_mfma_f32_16x16x32_bf16(pl[iT], ah, acc, 0, 0, 0);
            acc = __builtin_amdgcn_mfma_f32_16x16x32_bf16(ph[iT], al, acc, 0, 0, 0);
#pragma unroll
            for (int r = 0; r < 4; ++r) {
                int i = iT * 16 + qd * 4 + r;          // 0..63
                U[((i >> 5) << 13) + u_idx(i & 31, dcol)] = __float_as_uint(acc[r]);
            }
        }
    }
    __syncthreads();

    // carries for both chunks (independent scan chains -> 2x ILP)
    int p0 = (blockIdx.x * 2) * LD + d;
    float ga0 = preA[p0],      gm0 = preBm[p0],      gv0 = preBv[p0];
    float ga1 = preA[p0 + LD], gm1 = preBm[p0 + LD], gv1 = preBv[p0 + LD];
    float i0 = im0[d], v0 = iv0[d], yvd = yv[d];

    int ubase = ((d >> 5) << 10) + (d & 7);
    int qb = (d >> 3) & 3;
    for (int g = 0; g < 4; ++g) {
        float av0[8], av1[8];
#pragma unroll
        for (int k = 0; k < 8; ++k) {
            av0[k] = alphas[(size_t)(bt0 + g * 8 + k) * LD + d];
            av1[k] = alphas[(size_t)(bt0 + 32 + g * 8 + k) * LD + d];
        }
#pragma unroll
        for (int k = 0; k < 8; ++k) {
            int i = g * 8 + k;
            int ui0 = ubase + (i << 5) + ((qb ^ (i & 3)) << 3);
            int ui1 = 8192 + ui0;
            float Am0 = __uint_as_float(U[ui0]);
            float Am1 = __uint_as_float(U[ui1]);
            float t0 = obs[bt0 + i];
            float t1 = obs[bt0 + 32 + i];
            float e0 = __expf(Am0 * t0);
            float e1 = __expf(Am1 * t1);
            float r0 = __builtin_amdgcn_rcpf(Am0);
            float r1 = __builtin_amdgcn_rcpf(Am1);
            float q0 = e0 * e0, q1 = e1 * e1;
            float bm0 = (e0 - 1.f) * r0 * av0[k];
            float bm1 = (e1 - 1.f) * r1 * av1[k];
            float bv0 = fmaf(0.5f * (q0 - 1.f), r0, EPS);
            float bv1 = fmaf(0.5f * (q1 - 1.f), r1, EPS);
            gm0 = fmaf(e0, gm0, bm0);   gm1 = fmaf(e1, gm1, bm1);
            gv0 = fmaf(q0, gv0, bv0);   gv1 = fmaf(q1, gv1, bv1);
            ga0 *= e0;                  ga1 *= e1;
            float mm0 = fmaf(ga0, i0, gm0);
            float mm1 = fmaf(ga1, i0, gm1);
            float vv0 = fmaf(ga0 * ga0, v0, gv0) + yvd;
            float vv1 = fmaf(ga1 * ga1, v0, gv1) + yvd;
            float ss0 = sqrtf(vv0);
            float ss1 = sqrtf(vv1);
            U[ui0] = ((unsigned int)f2b(mm0) << 16) | (unsigned int)f2b(ss0);
            U[ui1] = ((unsigned int)f2b(mm1) << 16) | (unsigned int)f2b(ss1);
        }
    }
    __syncthreads();

    // ---- barrier-free MFMA GEMM phase, M=64 ----
    f32x4 accm[4][4], accs[4][4];
#pragma unroll
    for (int iT = 0; iT < 4; ++iT)
#pragma unroll
        for (int j = 0; j < 4; ++j) {
            accm[iT][j] = (f32x4){0.f, 0.f, 0.f, 0.f};
            accs[iT][j] = (f32x4){0.f, 0.f, 0.f, 0.f};
        }
    for (int kc = 0; kc < 8; ++kc) {
        bf16x8 am[4], asv[4], az[4];
#pragma unroll
        for (int iT = 0; iT < 4; ++iT) {
            int row = iT * 16 + mr;                    // 0..63
            int ii = row & 31;
            int off = ((row >> 5) << 13) + (kc << 10) + (ii << 5) + ((qd ^ (ii & 3)) << 3);
            uint4 ua = *(const uint4*)(U + off);
            uint4 ub = *(const uint4*)(U + off + 4);
            unsigned int uu[8] = {ua.x, ua.y, ua.z, ua.w, ub.x, ub.y, ub.z, ub.w};
            bf16x8 m_, s_;
#pragma unroll
            for (int k = 0; k < 8; ++k) {
                m_[k] = (short)(uu[k] >> 16);
                s_[k] = (short)(uu[k] & 0xffffu);
            }
            am[iT] = m_; asv[iT] = s_;
            az[iT] = *(const bf16x8*)(Zh + (size_t)(bt0 + row) * LD + kc * 32 + qd * 8);
        }
#pragma unroll
        for (int j = 0; j < 4; ++j) {
            int brow = wv * 64 + j * 16 + mr;
            bf16x8 bm = *(const bf16x8*)(GMh + (size_t)brow * LD + kc * 32 + qd * 8);
            bf16x8 bc = *(const bf16x8*)(GCh + (size_t)brow * LD + kc * 32 + qd * 8);
#pragma unroll
            for (int iT = 0; iT < 4; ++iT) {
                accm[iT][j] = __builtin_amdgcn_mfma_f32_16x16x32_bf16(am[iT],  bm, accm[iT][j], 0, 0, 0);
                accs[iT][j] = __builtin_amdgcn_mfma_f32_16x16x32_bf16(asv[iT], bm, accs[iT][j], 0, 0, 0);
                accm[iT][j] = __builtin_amdgcn_mfma_f32_16x16x32_bf16(az[iT],  bc, accm[iT][j], 0, 0, 0);
            }
        }
    }

    // ---- epilogue ----
    int col0 = wv * 64 + mr;
    int rb   = (lane >> 4) << 2;
#pragma unroll
    for (int iT = 0; iT < 4; ++iT)
#pragma unroll
        for (int j = 0; j < 4; ++j)
#pragma unroll
            for (int r = 0; r < 4; ++r) {
                size_t off = (size_t)(bt0 + iT * 16 + rb + r) * LD + col0 + j * 16;
                means[off] = accm[iT][j][r];
                stds[off]  = accs[iT][j][r];
            }
}

// ---------------------------------------------------------------------------
extern "C" void kernel_launch(void* const* d_in, const int* in_sizes, int n_in,
                              void* d_out, int out_size, void* d_ws, size_t ws_size,
                              hipStream_t stream) {
    const float* Z   = (const float*)d_in[0];
    const float* obs = (const float*)d_in[1];
    const float* Dm  = (const float*)d_in[2];
    const float* cw  = (const float*)d_in[3];
    const float* cb  = (const float*)d_in[4];
    const float* Ew  = (const float*)d_in[5];
    const float* Bw  = (const float*)d_in[6];
    const float* Cw  = (const float*)d_in[7];
    const float* Mw  = (const float*)d_in[8];
    const float* imp = (const float*)d_in[9];
    const float* ilv = (const float*)d_in[10];
    const float* ylv = (const float*)d_in[11];

    float* out    = (float*)d_out;
    float* means  = out;
    float* stds   = out + (size_t)BT * LD;
    float* alphas = out + (size_t)2 * BT * LD;

    char* ws = (char*)d_ws;
    size_t o = 0;
    unsigned short* Zh   = (unsigned short*)(ws + o); o += (size_t)BT * LD * 2;   // 16MB
    float*          logits=(float*)(ws + o);          o += (size_t)BT * NB * 4;   // 4MB
    unsigned short* GMh  = (unsigned short*)(ws + o); o += (size_t)LD * LD * 2;
    unsigned short* GCh  = (unsigned short*)(ws + o); o += (size_t)LD * LD * 2;
    unsigned short* Bwh  = (unsigned short*)(ws + o); o += (size_t)LD * LD * 2;
    unsigned short* cwbh = (unsigned short*)(ws + o); o += (size_t)NB * LD * 2;
    unsigned short* AbTh = (unsigned short*)(ws + o); o += (size_t)LD * NB * 2;
    unsigned short* AbTl = (unsigned short*)(ws + o); o += (size_t)LD * NB * 2;
    float* totA  = (float*)(ws + o); o += (size_t)B_ * NCH * LD * 4;
    float* totBm = (float*)(ws + o); o += (size_t)B_ * NCH * LD * 4;
    float* totBv = (float*)(ws + o); o += (size_t)B_ * NCH * LD * 4;
    float* preA  = (float*)(ws + o); o += (size_t)B_ * NCH * LD * 4;
    float* preBm = (float*)(ws + o); o += (size_t)B_ * NCH * LD * 4;
    float* preBv = (float*)(ws + o); o += (size_t)B_ * NCH * LD * 4;
    float* im0   = (float*)(ws + o); o += LD * 4;
    float* iv0   = (float*)(ws + o); o += LD * 4;
    float* yv    = (float*)(ws + o); o += LD * 4;

    // 1. all precompute
    k_pre<<<dim3(641 + BT * LD / 1024), dim3(256), 0, stream>>>(
        Z, Dm, cw, Ew, Bw, Cw, Mw, imp, ilv, ylv,
        GMh, GCh, cwbh, im0, iv0, yv, AbTh, AbTl, Bwh, Zh);

    // 2. alphas + logits (both straight from Zh)
    k_zb<<<dim3(BT / 128, 3), dim3(256), 0, stream>>>(Zh, Bwh, cwbh, cb, alphas, logits);

    // 3-4. chunk totals + prefix
    k_tot<<<dim3(B_ * NCH), dim3(256), 0, stream>>>(logits, alphas, obs, AbTh, AbTl,
                                                    totA, totBm, totBv);
    k_chunkpfx<<<dim3(B_), dim3(LD), 0, stream>>>(totA, totBm, totBv, preA, preBm, preBv);

    // 5. fused scan + means/stds GEMMs (one block = 2 chunks)
    k_sms<<<dim3(B_ * NCH / 2), dim3(256), 0, stream>>>(logits, alphas, obs, AbTh, AbTl,
                                                        preA, preBm, preBv,
                                                        im0, iv0, yv,
                                                        Zh, GMh, GCh, means, stds);
}